// Round 2
// baseline (493.714 us; speedup 1.0000x reference)
//
#include <hip/hip_runtime.h>
#include <math.h>

#define NEG_SLOPE 0.2f

__device__ __forceinline__ float lrelu(float x){ return x > 0.f ? x : NEG_SLOPE * x; }
__device__ __forceinline__ float elu_f(float x){ return x > 0.f ? x : expm1f(x); }

// ---------------- CSR build ----------------
__global__ void k_hist(const int* __restrict__ dst, int E, int* __restrict__ cnt){
  int i = blockIdx.x * blockDim.x + threadIdx.x;
  if (i < E) atomicAdd(&cnt[dst[i]], 1);
}

__global__ void k_scanA(const int* __restrict__ cnt, int n, int* __restrict__ off, int* __restrict__ sums){
  __shared__ int tmp[1024];
  int tid = threadIdx.x;
  int i = blockIdx.x * 1024 + tid;
  int v = (i < n) ? cnt[i] : 0;
  tmp[tid] = v; __syncthreads();
  for (int o = 1; o < 1024; o <<= 1){
    int t = (tid >= o) ? tmp[tid - o] : 0;
    __syncthreads();
    tmp[tid] += t;
    __syncthreads();
  }
  if (i < n) off[i] = tmp[tid] - v;          // exclusive within block
  if (tid == 1023) sums[blockIdx.x] = tmp[tid];
}

__global__ void k_scanB(int* __restrict__ sums, int nb){
  __shared__ int tmp[1024];
  int tid = threadIdx.x;
  int v = (tid < nb) ? sums[tid] : 0;
  tmp[tid] = v; __syncthreads();
  for (int o = 1; o < 1024; o <<= 1){
    int t = (tid >= o) ? tmp[tid - o] : 0;
    __syncthreads();
    tmp[tid] += t;
    __syncthreads();
  }
  if (tid < nb) sums[tid] = tmp[tid] - v;    // exclusive block offsets
}

__global__ void k_scanC(int* __restrict__ off, const int* __restrict__ sums, int n, int E){
  int i = blockIdx.x * 1024 + threadIdx.x;
  if (i < n) off[i] += sums[blockIdx.x];
  if (i == 0) off[n] = E;
}

__global__ void k_scatter(const int* __restrict__ src, const int* __restrict__ dst, int E,
                          const int* __restrict__ off, int* __restrict__ cur, int* __restrict__ col){
  int i = blockIdx.x * blockDim.x + threadIdx.x;
  if (i < E){
    int d = dst[i];
    int p = off[d] + atomicAdd(&cur[d], 1);
    col[p] = src[i];
  }
}

// ---------------- node GEMM: H = X @ W  (+ attention logits) ----------------
// Block: 256 threads, 64 nodes x 64 channels per block. Per-thread tile 4x4.
template<int K>
__global__ __launch_bounds__(256) void k_gemm(
    const float* __restrict__ X,      // [n, K]
    const float* __restrict__ W,      // [K, 64]
    const float* __restrict__ a_src, const float* __restrict__ a_dst,  // [64]
    float* __restrict__ H,            // [n, 64]
    float* __restrict__ as_, float* __restrict__ ad_, int n)
{
  __shared__ float sW[K * 64];
  __shared__ float sX[32 * 68];       // 32 k x 64 nodes, stride 68 (16B-aligned rows, bank-skewed)
  const int tid = threadIdx.x;
  for (int i = tid; i < K * 16; i += 256)
    ((float4*)sW)[i] = ((const float4*)W)[i];

  const int cg = tid & 15;            // channel group (4 channels)
  const int nr = tid >> 4;            // node row (4 nodes)
  const int nodeBase = blockIdx.x * 64;
  float acc[4][4] = {};

  for (int kc = 0; kc < K; kc += 32){
    __syncthreads();
    for (int e = tid; e < 64 * 32; e += 256){
      int nn = e >> 5, kk = e & 31;
      int gn = nodeBase + nn; if (gn >= n) gn = n - 1;
      sX[kk * 68 + nn] = X[(long)gn * K + kc + kk];
    }
    __syncthreads();
    #pragma unroll
    for (int kk = 0; kk < 32; ++kk){
      float4 xv = *(const float4*)&sX[kk * 68 + nr * 4];
      float4 wv = *(const float4*)&sW[(kc + kk) * 64 + cg * 4];
      float xs[4] = {xv.x, xv.y, xv.z, xv.w};
      float ws[4] = {wv.x, wv.y, wv.z, wv.w};
      #pragma unroll
      for (int a = 0; a < 4; ++a)
        #pragma unroll
        for (int b = 0; b < 4; ++b)
          acc[a][b] = fmaf(xs[a], ws[b], acc[a][b]);
    }
  }

  float a_s[4], a_d[4];
  #pragma unroll
  for (int c = 0; c < 4; ++c){ a_s[c] = a_src[cg * 4 + c]; a_d[c] = a_dst[cg * 4 + c]; }
  #pragma unroll
  for (int i2 = 0; i2 < 4; ++i2){
    int gn = nodeBase + nr * 4 + i2;
    float s = acc[i2][0]*a_s[0] + acc[i2][1]*a_s[1] + acc[i2][2]*a_s[2] + acc[i2][3]*a_s[3];
    float d = acc[i2][0]*a_d[0] + acc[i2][1]*a_d[1] + acc[i2][2]*a_d[2] + acc[i2][3]*a_d[3];
    #pragma unroll
    for (int o = 1; o < 16; o <<= 1){ s += __shfl_xor(s, o, 64); d += __shfl_xor(d, o, 64); }
    if (gn < n){
      float4 hv = make_float4(acc[i2][0], acc[i2][1], acc[i2][2], acc[i2][3]);
      *(float4*)&H[(long)gn * 64 + cg * 4] = hv;
      if (cg == 0){ as_[gn] = s; ad_[gn] = d; }
    }
  }
}

// ---------------- per-node attention aggregation (one wave per node) ----------------
// outH[n][d] = elu( (sum_j ex_j * H[src_j][d]) / (sum_j ex_j) + bias[d] )
__global__ __launch_bounds__(256) void k_agg1(
    const int* __restrict__ off, const int* __restrict__ col,
    const float* __restrict__ H, const float* __restrict__ as_, const float* __restrict__ ad_,
    const float* __restrict__ bias, float* __restrict__ outH, int n)
{
  __shared__ float s_ex[4][64];
  __shared__ int   s_col[4][64];
  int w = threadIdx.x >> 6, lane = threadIdx.x & 63;
  int node = blockIdx.x * 4 + w;
  if (node >= n) return;
  int beg = off[node], end = off[node + 1];
  float adv = ad_[node];
  float e_self = lrelu(as_[node] + adv);
  // pass 1: segment max (lane-parallel over in-edges; self-loop included)
  float mloc = e_self;
  for (int j = beg + lane; j < end; j += 64)
    mloc = fmaxf(mloc, lrelu(as_[col[j]] + adv));
  #pragma unroll
  for (int o = 32; o > 0; o >>= 1) mloc = fmaxf(mloc, __shfl_xor(mloc, o, 64));
  float m = mloc;
  // pass 2: chunked exp + weighted accumulate (normalize at end)
  float denom = 0.f, acc = 0.f;
  for (int cb = beg; cb < end; cb += 64){
    int cnt = end - cb; if (cnt > 64) cnt = 64;
    float ex = 0.f; int s = 0;
    if (lane < cnt){ s = col[cb + lane]; ex = expf(lrelu(as_[s] + adv) - m); }
    s_ex[w][lane] = ex; s_col[w][lane] = s;   // wave-local LDS, no barrier needed
    for (int j = 0; j < cnt; ++j){
      float exj = s_ex[w][j];
      int   sj  = s_col[w][j];
      denom += exj;
      acc = fmaf(exj, H[(long)sj * 64 + lane], acc);
    }
  }
  float exs = expf(e_self - m);
  denom += exs;
  acc = fmaf(exs, H[(long)node * 64 + lane], acc);
  float v = acc / denom + bias[lane];
  outH[(long)node * 64 + lane] = elu_f(v);
}

// layer-2 aggregation fused with elu + output head: out[n] = elu(gat2)[:] . Wout + bout
__global__ __launch_bounds__(256) void k_agg2(
    const int* __restrict__ off, const int* __restrict__ col,
    const float* __restrict__ H, const float* __restrict__ as_, const float* __restrict__ ad_,
    const float* __restrict__ bias, const float* __restrict__ Wout, const float* __restrict__ bout,
    float* __restrict__ out, int n)
{
  __shared__ float s_ex[4][64];
  __shared__ int   s_col[4][64];
  int w = threadIdx.x >> 6, lane = threadIdx.x & 63;
  int node = blockIdx.x * 4 + w;
  if (node >= n) return;
  int beg = off[node], end = off[node + 1];
  float adv = ad_[node];
  float e_self = lrelu(as_[node] + adv);
  float mloc = e_self;
  for (int j = beg + lane; j < end; j += 64)
    mloc = fmaxf(mloc, lrelu(as_[col[j]] + adv));
  #pragma unroll
  for (int o = 32; o > 0; o >>= 1) mloc = fmaxf(mloc, __shfl_xor(mloc, o, 64));
  float m = mloc;
  float denom = 0.f, acc = 0.f;
  for (int cb = beg; cb < end; cb += 64){
    int cnt = end - cb; if (cnt > 64) cnt = 64;
    float ex = 0.f; int s = 0;
    if (lane < cnt){ s = col[cb + lane]; ex = expf(lrelu(as_[s] + adv) - m); }
    s_ex[w][lane] = ex; s_col[w][lane] = s;
    for (int j = 0; j < cnt; ++j){
      float exj = s_ex[w][j];
      int   sj  = s_col[w][j];
      denom += exj;
      acc = fmaf(exj, H[(long)sj * 64 + lane], acc);
    }
  }
  float exs = expf(e_self - m);
  denom += exs;
  acc = fmaf(exs, H[(long)node * 64 + lane], acc);
  float v = elu_f(acc / denom + bias[lane]);
  float p = v * Wout[lane];
  #pragma unroll
  for (int o = 32; o > 0; o >>= 1) p += __shfl_xor(p, o, 64);
  if (lane == 0) out[node] = p + bout[0];
}

// ---------------- launch ----------------
extern "C" void kernel_launch(void* const* d_in, const int* in_sizes, int n_in,
                              void* d_out, int out_size, void* d_ws, size_t ws_size,
                              hipStream_t stream)
{
  const float* x    = (const float*)d_in[0];
  const int*   ei   = (const int*)d_in[1];   // harness stores integer inputs as int32; [2, E] flat
  const float* W1   = (const float*)d_in[2];
  const float* as1w = (const float*)d_in[3];
  const float* ad1w = (const float*)d_in[4];
  const float* b1   = (const float*)d_in[5];
  const float* W2   = (const float*)d_in[6];
  const float* as2w = (const float*)d_in[7];
  const float* ad2w = (const float*)d_in[8];
  const float* b2   = (const float*)d_in[9];
  const float* Wout = (const float*)d_in[10];
  const float* bout = (const float*)d_in[11];
  float* out = (float*)d_out;

  const int N = in_sizes[0] / 128;
  const int E = in_sizes[1] / 2;
  const int* srcA = ei;
  const int* dstA = ei + E;

  char* p = (char*)d_ws;
  auto alloc = [&](size_t bytes){ char* r = p; p += (bytes + 255) & ~255ull; return r; };
  int*   cnt  = (int*)alloc((size_t)N * 4);
  int*   cur  = (int*)alloc((size_t)N * 4);
  int*   offs = (int*)alloc((size_t)(N + 1) * 4);
  int*   sums = (int*)alloc(1024 * 4);
  int*   col  = (int*)alloc((size_t)E * 4);
  float* vas1 = (float*)alloc((size_t)N * 4);
  float* vad1 = (float*)alloc((size_t)N * 4);
  float* vas2 = (float*)alloc((size_t)N * 4);
  float* vad2 = (float*)alloc((size_t)N * 4);
  float* h1   = (float*)alloc((size_t)N * 64 * 4);
  float* h1e  = (float*)alloc((size_t)N * 64 * 4);
  float* h2   = h1;   // h1 is dead after k_agg1; reuse for layer-2 features

  hipMemsetAsync(cnt, 0, (size_t)N * 4, stream);
  hipMemsetAsync(cur, 0, (size_t)N * 4, stream);

  int nb = (N + 1023) / 1024;
  k_hist   <<<(E + 255) / 256, 256, 0, stream>>>(dstA, E, cnt);
  k_scanA  <<<nb, 1024, 0, stream>>>(cnt, N, offs, sums);
  k_scanB  <<<1, 1024, 0, stream>>>(sums, nb);
  k_scanC  <<<nb, 1024, 0, stream>>>(offs, sums, N, E);
  k_scatter<<<(E + 255) / 256, 256, 0, stream>>>(srcA, dstA, E, offs, cur, col);

  k_gemm<128><<<(N + 63) / 64, 256, 0, stream>>>(x, W1, as1w, ad1w, h1, vas1, vad1, N);
  k_agg1     <<<(N + 3) / 4, 256, 0, stream>>>(offs, col, h1, vas1, vad1, b1, h1e, N);
  k_gemm<64> <<<(N + 63) / 64, 256, 0, stream>>>(h1e, W2, as2w, ad2w, h2, vas2, vad2, N);
  k_agg2     <<<(N + 3) / 4, 256, 0, stream>>>(offs, col, h2, vas2, vad2, b2, Wout, bout, out, N);
}

// Round 3
// 387.350 us; speedup vs baseline: 1.2746x; 1.2746x over previous
//
#include <hip/hip_runtime.h>
#include <math.h>

#define NEG_SLOPE 0.2f
#define BKT_SHIFT 10
#define BKT_NODES (1 << BKT_SHIFT)
#define BKT_CAP 128
#define P1_CHUNK 16384

__device__ __forceinline__ float lrelu(float x){ return x > 0.f ? x : NEG_SLOPE * x; }
__device__ __forceinline__ float elu_f(float x){ return x > 0.f ? x : expm1f(x); }

// ---------------- bucketed CSR build ----------------
// bucket b = dst >> BKT_SHIFT; per-bucket contiguous regions in pairs/col.

__global__ __launch_bounds__(256) void k_bh(const int* __restrict__ dst, int E, int B,
                                            int* __restrict__ bktTot){
  __shared__ int h[BKT_CAP];
  int tid = threadIdx.x;
  if (tid < BKT_CAP) h[tid] = 0;
  __syncthreads();
  int beg = blockIdx.x * P1_CHUNK;
  int end = min(beg + P1_CHUNK, E);
  for (int i = beg + tid; i < end; i += 256)
    atomicAdd(&h[dst[i] >> BKT_SHIFT], 1);
  __syncthreads();
  if (tid < B && h[tid]) atomicAdd(&bktTot[tid], h[tid]);
}

__global__ void k_bscan(const int* __restrict__ bktTot, int B, int E, int N,
                        int* __restrict__ bktStart, int* __restrict__ bktCur,
                        int* __restrict__ offs){
  __shared__ int tmp[BKT_CAP];
  int t = threadIdx.x;               // 128 threads
  int v = (t < B) ? bktTot[t] : 0;
  tmp[t] = v; __syncthreads();
  for (int o = 1; o < BKT_CAP; o <<= 1){
    int x = (t >= o) ? tmp[t - o] : 0;
    __syncthreads();
    tmp[t] += x;
    __syncthreads();
  }
  if (t < B){ int st = tmp[t] - v; bktStart[t] = st; bktCur[t] = st; }
  if (t == 0){ bktStart[B] = E; offs[N] = E; }
}

__global__ __launch_bounds__(256) void k_p1(const int* __restrict__ src, const int* __restrict__ dst,
                                            int E, int B, int* __restrict__ bktCur,
                                            int2* __restrict__ pairs){
  __shared__ int h[BKT_CAP], base[BKT_CAP], cur[BKT_CAP];
  int tid = threadIdx.x;
  if (tid < BKT_CAP){ h[tid] = 0; cur[tid] = 0; }
  __syncthreads();
  int beg = blockIdx.x * P1_CHUNK;
  int end = min(beg + P1_CHUNK, E);
  for (int i = beg + tid; i < end; i += 256)
    atomicAdd(&h[dst[i] >> BKT_SHIFT], 1);
  __syncthreads();
  if (tid < B && h[tid]) base[tid] = atomicAdd(&bktCur[tid], h[tid]);
  __syncthreads();
  for (int i = beg + tid; i < end; i += 256){
    int d = dst[i], s = src[i];
    int b = d >> BKT_SHIFT;
    int p = base[b] + atomicAdd(&cur[b], 1);
    pairs[p] = make_int2(d, s);
  }
}

// one block per bucket: LDS node-hist -> in-block scan -> offs + col (LDS cursors)
__global__ __launch_bounds__(256) void k_p2(const int2* __restrict__ pairs,
                                            const int* __restrict__ bktStart,
                                            int N, int* __restrict__ offs, int* __restrict__ col){
  __shared__ int sc[BKT_NODES], cu[BKT_NODES], tsum[256];
  int b = blockIdx.x, tid = threadIdx.x;
  int nbase = b << BKT_SHIFT;
  int bs = bktStart[b], be = bktStart[b + 1];
  for (int i = tid; i < BKT_NODES; i += 256) sc[i] = 0;
  __syncthreads();
  for (int i = bs + tid; i < be; i += 256)
    atomicAdd(&sc[pairs[i].x - nbase], 1);
  __syncthreads();
  // exclusive scan of sc[0..1023] (4 elems/thread + block scan over thread sums)
  int v0 = sc[tid*4], v1 = sc[tid*4+1], v2 = sc[tid*4+2], v3 = sc[tid*4+3];
  int s = v0 + v1 + v2 + v3;
  tsum[tid] = s; __syncthreads();
  for (int o = 1; o < 256; o <<= 1){
    int x = (tid >= o) ? tsum[tid - o] : 0;
    __syncthreads();
    tsum[tid] += x;
    __syncthreads();
  }
  int ex0 = tsum[tid] - s;
  sc[tid*4]   = ex0;
  sc[tid*4+1] = ex0 + v0;
  sc[tid*4+2] = ex0 + v0 + v1;
  sc[tid*4+3] = ex0 + v0 + v1 + v2;
  __syncthreads();
  for (int i = tid; i < BKT_NODES; i += 256) cu[i] = sc[i];
  int wend = N - nbase; if (wend > BKT_NODES) wend = BKT_NODES;
  for (int i = tid; i < wend; i += 256) offs[nbase + i] = bs + sc[i];
  __syncthreads();
  for (int i = bs + tid; i < be; i += 256){
    int2 pr = pairs[i];
    int p = bs + atomicAdd(&cu[pr.x - nbase], 1);
    col[p] = pr.y;
  }
}

// ---------------- node GEMM: H = X @ W  (+ attention logits) ----------------
template<int K>
__global__ __launch_bounds__(256) void k_gemm(
    const float* __restrict__ X, const float* __restrict__ W,
    const float* __restrict__ a_src, const float* __restrict__ a_dst,
    float* __restrict__ H, float* __restrict__ as_, float* __restrict__ ad_, int n)
{
  __shared__ float sW[K * 64];
  __shared__ float sX[32 * 68];
  const int tid = threadIdx.x;
  for (int i = tid; i < K * 16; i += 256)
    ((float4*)sW)[i] = ((const float4*)W)[i];

  const int cg = tid & 15;
  const int nr = tid >> 4;
  const int nodeBase = blockIdx.x * 64;
  float acc[4][4] = {};

  for (int kc = 0; kc < K; kc += 32){
    __syncthreads();
    for (int e = tid; e < 64 * 32; e += 256){
      int nn = e >> 5, kk = e & 31;
      int gn = nodeBase + nn; if (gn >= n) gn = n - 1;
      sX[kk * 68 + nn] = X[(long)gn * K + kc + kk];
    }
    __syncthreads();
    #pragma unroll
    for (int kk = 0; kk < 32; ++kk){
      float4 xv = *(const float4*)&sX[kk * 68 + nr * 4];
      float4 wv = *(const float4*)&sW[(kc + kk) * 64 + cg * 4];
      float xs[4] = {xv.x, xv.y, xv.z, xv.w};
      float ws[4] = {wv.x, wv.y, wv.z, wv.w};
      #pragma unroll
      for (int a = 0; a < 4; ++a)
        #pragma unroll
        for (int b = 0; b < 4; ++b)
          acc[a][b] = fmaf(xs[a], ws[b], acc[a][b]);
    }
  }

  float a_s[4], a_d[4];
  #pragma unroll
  for (int c = 0; c < 4; ++c){ a_s[c] = a_src[cg * 4 + c]; a_d[c] = a_dst[cg * 4 + c]; }
  #pragma unroll
  for (int i2 = 0; i2 < 4; ++i2){
    int gn = nodeBase + nr * 4 + i2;
    float sl = acc[i2][0]*a_s[0] + acc[i2][1]*a_s[1] + acc[i2][2]*a_s[2] + acc[i2][3]*a_s[3];
    float dl = acc[i2][0]*a_d[0] + acc[i2][1]*a_d[1] + acc[i2][2]*a_d[2] + acc[i2][3]*a_d[3];
    #pragma unroll
    for (int o = 1; o < 16; o <<= 1){ sl += __shfl_xor(sl, o, 64); dl += __shfl_xor(dl, o, 64); }
    if (gn < n){
      float4 hv = make_float4(acc[i2][0], acc[i2][1], acc[i2][2], acc[i2][3]);
      *(float4*)&H[(long)gn * 64 + cg * 4] = hv;
      if (cg == 0){ as_[gn] = sl; ad_[gn] = dl; }
    }
  }
}

// ---------------- attention aggregation (one wave per node; no max pass) ----------------
__global__ __launch_bounds__(256) void k_agg1(
    const int* __restrict__ off, const int* __restrict__ col,
    const float* __restrict__ H, const float* __restrict__ as_, const float* __restrict__ ad_,
    const float* __restrict__ bias, float* __restrict__ outH, int n)
{
  __shared__ float s_ex[4][64];
  __shared__ int   s_col[4][64];
  int w = threadIdx.x >> 6, lane = threadIdx.x & 63;
  int node = blockIdx.x * 4 + w;
  if (node >= n) return;
  int beg = off[node], end = off[node + 1];
  float adv = ad_[node];
  float denom = 0.f, acc = 0.f;
  for (int cb = beg; cb < end; cb += 64){
    int cnt = end - cb; if (cnt > 64) cnt = 64;
    float ex = 0.f; int s = 0;
    if (lane < cnt){ s = col[cb + lane]; ex = expf(lrelu(as_[s] + adv)); }
    s_ex[w][lane] = ex; s_col[w][lane] = s;   // wave-local, lockstep: no barrier
    int j = 0;
    for (; j + 4 <= cnt; j += 4){
      float e0 = s_ex[w][j],   e1 = s_ex[w][j+1], e2 = s_ex[w][j+2], e3 = s_ex[w][j+3];
      int   i0 = s_col[w][j],  i1 = s_col[w][j+1], i2 = s_col[w][j+2], i3 = s_col[w][j+3];
      float h0 = H[(long)i0*64 + lane], h1 = H[(long)i1*64 + lane];
      float h2 = H[(long)i2*64 + lane], h3 = H[(long)i3*64 + lane];
      denom += (e0 + e1) + (e2 + e3);
      acc = fmaf(e0, h0, fmaf(e1, h1, fmaf(e2, h2, fmaf(e3, h3, acc))));
    }
    for (; j < cnt; ++j){
      float e = s_ex[w][j]; int sj = s_col[w][j];
      denom += e;
      acc = fmaf(e, H[(long)sj*64 + lane], acc);
    }
  }
  float exs = expf(lrelu(as_[node] + adv));
  denom += exs;
  acc = fmaf(exs, H[(long)node*64 + lane], acc);
  float v = acc / denom + bias[lane];
  outH[(long)node*64 + lane] = elu_f(v);
}

__global__ __launch_bounds__(256) void k_agg2(
    const int* __restrict__ off, const int* __restrict__ col,
    const float* __restrict__ H, const float* __restrict__ as_, const float* __restrict__ ad_,
    const float* __restrict__ bias, const float* __restrict__ Wout, const float* __restrict__ bout,
    float* __restrict__ out, int n)
{
  __shared__ float s_ex[4][64];
  __shared__ int   s_col[4][64];
  int w = threadIdx.x >> 6, lane = threadIdx.x & 63;
  int node = blockIdx.x * 4 + w;
  if (node >= n) return;
  int beg = off[node], end = off[node + 1];
  float adv = ad_[node];
  float denom = 0.f, acc = 0.f;
  for (int cb = beg; cb < end; cb += 64){
    int cnt = end - cb; if (cnt > 64) cnt = 64;
    float ex = 0.f; int s = 0;
    if (lane < cnt){ s = col[cb + lane]; ex = expf(lrelu(as_[s] + adv)); }
    s_ex[w][lane] = ex; s_col[w][lane] = s;
    int j = 0;
    for (; j + 4 <= cnt; j += 4){
      float e0 = s_ex[w][j],   e1 = s_ex[w][j+1], e2 = s_ex[w][j+2], e3 = s_ex[w][j+3];
      int   i0 = s_col[w][j],  i1 = s_col[w][j+1], i2 = s_col[w][j+2], i3 = s_col[w][j+3];
      float h0 = H[(long)i0*64 + lane], h1 = H[(long)i1*64 + lane];
      float h2 = H[(long)i2*64 + lane], h3 = H[(long)i3*64 + lane];
      denom += (e0 + e1) + (e2 + e3);
      acc = fmaf(e0, h0, fmaf(e1, h1, fmaf(e2, h2, fmaf(e3, h3, acc))));
    }
    for (; j < cnt; ++j){
      float e = s_ex[w][j]; int sj = s_col[w][j];
      denom += e;
      acc = fmaf(e, H[(long)sj*64 + lane], acc);
    }
  }
  float exs = expf(lrelu(as_[node] + adv));
  denom += exs;
  acc = fmaf(exs, H[(long)node*64 + lane], acc);
  float v = elu_f(acc / denom + bias[lane]);
  float p = v * Wout[lane];
  #pragma unroll
  for (int o = 32; o > 0; o >>= 1) p += __shfl_xor(p, o, 64);
  if (lane == 0) out[node] = p + bout[0];
}

// ---------------- launch ----------------
extern "C" void kernel_launch(void* const* d_in, const int* in_sizes, int n_in,
                              void* d_out, int out_size, void* d_ws, size_t ws_size,
                              hipStream_t stream)
{
  const float* x    = (const float*)d_in[0];
  const int*   ei   = (const int*)d_in[1];   // int32 [2, E] flat
  const float* W1   = (const float*)d_in[2];
  const float* as1w = (const float*)d_in[3];
  const float* ad1w = (const float*)d_in[4];
  const float* b1   = (const float*)d_in[5];
  const float* W2   = (const float*)d_in[6];
  const float* as2w = (const float*)d_in[7];
  const float* ad2w = (const float*)d_in[8];
  const float* b2   = (const float*)d_in[9];
  const float* Wout = (const float*)d_in[10];
  const float* bout = (const float*)d_in[11];
  float* out = (float*)d_out;

  const int N = in_sizes[0] / 128;
  const int E = in_sizes[1] / 2;
  const int* srcA = ei;
  const int* dstA = ei + E;
  const int B = (N + BKT_NODES - 1) >> BKT_SHIFT;   // 98 for N=100000 (<= BKT_CAP)

  char* p = (char*)d_ws;
  auto alloc = [&](size_t bytes){ char* r = p; p += (bytes + 255) & ~255ull; return r; };
  int*   bktTot   = (int*)alloc(BKT_CAP * 4);
  int*   bktStart = (int*)alloc((BKT_CAP + 1) * 4);
  int*   bktCur   = (int*)alloc(BKT_CAP * 4);
  int*   offs     = (int*)alloc((size_t)(N + 1) * 4);
  int*   col      = (int*)alloc((size_t)E * 4);
  float* vas1 = (float*)alloc((size_t)N * 4);
  float* vad1 = (float*)alloc((size_t)N * 4);
  float* vas2 = (float*)alloc((size_t)N * 4);
  float* vad2 = (float*)alloc((size_t)N * 4);
  float* h1   = (float*)alloc((size_t)N * 64 * 4);
  float* h1e  = (float*)alloc((size_t)N * 64 * 4);
  int2*  pairs = (int2*)h1;   // pairs (E*8B) dead before k_gemm writes h1 (N*256B)
  float* h2   = h1;           // h1 dead after k_agg1; reuse for layer-2 features

  hipMemsetAsync(bktTot, 0, BKT_CAP * 4, stream);

  int nchunk = (E + P1_CHUNK - 1) / P1_CHUNK;
  k_bh   <<<nchunk, 256, 0, stream>>>(dstA, E, B, bktTot);
  k_bscan<<<1, BKT_CAP, 0, stream>>>(bktTot, B, E, N, bktStart, bktCur, offs);
  k_p1   <<<nchunk, 256, 0, stream>>>(srcA, dstA, E, B, bktCur, pairs);
  k_p2   <<<B, 256, 0, stream>>>(pairs, bktStart, N, offs, col);

  k_gemm<128><<<(N + 63) / 64, 256, 0, stream>>>(x, W1, as1w, ad1w, h1, vas1, vad1, N);
  k_agg1     <<<(N + 3) / 4, 256, 0, stream>>>(offs, col, h1, vas1, vad1, b1, h1e, N);
  k_gemm<64> <<<(N + 63) / 64, 256, 0, stream>>>(h1e, W2, as2w, ad2w, h2, vas2, vad2, N);
  k_agg2     <<<(N + 3) / 4, 256, 0, stream>>>(offs, col, h2, vas2, vad2, b2, Wout, bout, out, N);
}

// Round 4
// 324.189 us; speedup vs baseline: 1.5229x; 1.1948x over previous
//
#include <hip/hip_runtime.h>
#include <hip/hip_fp16.h>
#include <math.h>

#define NEG_SLOPE 0.2f
#define BKT_SHIFT 10
#define BKT_NODES (1 << BKT_SHIFT)
#define BKT_CAP 128
#define P1_CHUNK 8192

__device__ __forceinline__ float lrelu(float x){ return x > 0.f ? x : NEG_SLOPE * x; }
__device__ __forceinline__ float elu_f(float x){ return x > 0.f ? x : expm1f(x); }

// ---------------- bucketed CSR build ----------------
// bucket b = dst >> BKT_SHIFT. pairs packed: (dst&1023)<<17 | src  (src < 2^17)

__global__ __launch_bounds__(256) void k_bh(const int* __restrict__ dst, int E, int B,
                                            int* __restrict__ bktTot){
  __shared__ int h[BKT_CAP];
  int tid = threadIdx.x;
  if (tid < BKT_CAP) h[tid] = 0;
  __syncthreads();
  int beg = blockIdx.x * P1_CHUNK;
  int end = min(beg + P1_CHUNK, E);
  for (int i = beg + tid; i < end; i += 256)
    atomicAdd(&h[dst[i] >> BKT_SHIFT], 1);
  __syncthreads();
  if (tid < B && h[tid]) atomicAdd(&bktTot[tid], h[tid]);
}

__global__ void k_bscan(const int* __restrict__ bktTot, int B, int E, int N,
                        int* __restrict__ bktStart, int* __restrict__ bktCur,
                        int* __restrict__ offs){
  __shared__ int tmp[BKT_CAP];
  int t = threadIdx.x;
  int v = (t < B) ? bktTot[t] : 0;
  tmp[t] = v; __syncthreads();
  for (int o = 1; o < BKT_CAP; o <<= 1){
    int x = (t >= o) ? tmp[t - o] : 0;
    __syncthreads();
    tmp[t] += x;
    __syncthreads();
  }
  if (t < B){ int st = tmp[t] - v; bktStart[t] = st; bktCur[t] = st; }
  if (t == 0){ bktStart[B] = E; offs[N] = E; }
}

__global__ __launch_bounds__(256) void k_p1(const int* __restrict__ src, const int* __restrict__ dst,
                                            int E, int B, int* __restrict__ bktCur,
                                            unsigned* __restrict__ pairs){
  __shared__ int h[BKT_CAP], base[BKT_CAP], cur[BKT_CAP];
  int tid = threadIdx.x;
  if (tid < BKT_CAP){ h[tid] = 0; cur[tid] = 0; }
  __syncthreads();
  int beg = blockIdx.x * P1_CHUNK;
  int end = min(beg + P1_CHUNK, E);
  for (int i = beg + tid; i < end; i += 256)
    atomicAdd(&h[dst[i] >> BKT_SHIFT], 1);
  __syncthreads();
  if (tid < B && h[tid]) base[tid] = atomicAdd(&bktCur[tid], h[tid]);
  __syncthreads();
  for (int i = beg + tid; i < end; i += 256){
    int d = dst[i], s = src[i];
    int b = d >> BKT_SHIFT;
    int p = base[b] + atomicAdd(&cur[b], 1);
    pairs[p] = ((unsigned)(d & (BKT_NODES - 1)) << 17) | (unsigned)s;
  }
}

// one block per bucket: LDS node-hist -> in-block scan -> offs + col
__global__ __launch_bounds__(1024) void k_p2(const unsigned* __restrict__ pairs,
                                             const int* __restrict__ bktStart,
                                             int N, int* __restrict__ offs, int* __restrict__ col){
  __shared__ int sc[BKT_NODES], cu[BKT_NODES];
  int b = blockIdx.x, tid = threadIdx.x;
  int nbase = b << BKT_SHIFT;
  int bs = bktStart[b], be = bktStart[b + 1];
  sc[tid] = 0;
  __syncthreads();
  for (int i = bs + tid; i < be; i += 1024)
    atomicAdd(&sc[pairs[i] >> 17], 1);
  __syncthreads();
  int v = sc[tid];
  for (int o = 1; o < 1024; o <<= 1){
    int x = (tid >= o) ? sc[tid - o] : 0;
    __syncthreads();
    sc[tid] += x;
    __syncthreads();
  }
  int ex = sc[tid] - v;
  cu[tid] = bs + ex;
  if (nbase + tid < N) offs[nbase + tid] = bs + ex;
  __syncthreads();
  for (int i = bs + tid; i < be; i += 1024){
    unsigned pr = pairs[i];
    int p = atomicAdd(&cu[pr >> 17], 1);
    col[p] = (int)(pr & 0x1FFFFu);
  }
}

// ---------------- node GEMM: H(fp16) = X @ W  (+ fp32 attention logits) ----------------
template<int K, bool HIN>
__global__ __launch_bounds__(256) void k_gemm(
    const void* __restrict__ Xv, const float* __restrict__ W,
    const float* __restrict__ a_src, const float* __restrict__ a_dst,
    uint2* __restrict__ H2, float* __restrict__ as_, float* __restrict__ ad_, int n)
{
  __shared__ float sW[K * 64];
  __shared__ float sX[32 * 68];
  const int tid = threadIdx.x;
  for (int i = tid; i < K * 16; i += 256)
    ((float4*)sW)[i] = ((const float4*)W)[i];

  const int cg = tid & 15;
  const int nr = tid >> 4;
  const int nodeBase = blockIdx.x * 64;
  float acc[4][4] = {};

  for (int kc = 0; kc < K; kc += 32){
    __syncthreads();
    for (int e = tid; e < 64 * 32; e += 256){
      int nn = e >> 5, kk = e & 31;
      int gn = nodeBase + nn; if (gn >= n) gn = n - 1;
      float xv;
      if (HIN) xv = __half2float(((const __half*)Xv)[(size_t)gn * K + kc + kk]);
      else     xv = ((const float*)Xv)[(size_t)gn * K + kc + kk];
      sX[kk * 68 + nn] = xv;
    }
    __syncthreads();
    #pragma unroll
    for (int kk = 0; kk < 32; ++kk){
      float4 xv = *(const float4*)&sX[kk * 68 + nr * 4];
      float4 wv = *(const float4*)&sW[(kc + kk) * 64 + cg * 4];
      float xs[4] = {xv.x, xv.y, xv.z, xv.w};
      float ws[4] = {wv.x, wv.y, wv.z, wv.w};
      #pragma unroll
      for (int a = 0; a < 4; ++a)
        #pragma unroll
        for (int b = 0; b < 4; ++b)
          acc[a][b] = fmaf(xs[a], ws[b], acc[a][b]);
    }
  }

  float a_s[4], a_d[4];
  #pragma unroll
  for (int c = 0; c < 4; ++c){ a_s[c] = a_src[cg * 4 + c]; a_d[c] = a_dst[cg * 4 + c]; }
  #pragma unroll
  for (int i2 = 0; i2 < 4; ++i2){
    int gn = nodeBase + nr * 4 + i2;
    float sl = acc[i2][0]*a_s[0] + acc[i2][1]*a_s[1] + acc[i2][2]*a_s[2] + acc[i2][3]*a_s[3];
    float dl = acc[i2][0]*a_d[0] + acc[i2][1]*a_d[1] + acc[i2][2]*a_d[2] + acc[i2][3]*a_d[3];
    #pragma unroll
    for (int o = 1; o < 16; o <<= 1){ sl += __shfl_xor(sl, o, 64); dl += __shfl_xor(dl, o, 64); }
    if (gn < n){
      __half2 h01 = __floats2half2_rn(acc[i2][0], acc[i2][1]);
      __half2 h23 = __floats2half2_rn(acc[i2][2], acc[i2][3]);
      uint2 ov; ov.x = *(unsigned*)&h01; ov.y = *(unsigned*)&h23;
      H2[(size_t)gn * 16 + cg] = ov;
      if (cg == 0){ as_[gn] = sl; ad_[gn] = dl; }
    }
  }
}

// ---------------- attention aggregation: 4 edges/wave-iter, fp16 H gather ----------------
// lane = (sub=lane>>4 -> edge j+sub, c=lane&15 -> channels 4c..4c+3)
__global__ __launch_bounds__(256) void k_agg1(
    const int* __restrict__ off, const int* __restrict__ col,
    const uint2* __restrict__ H2, const float* __restrict__ as_, const float* __restrict__ ad_,
    const float* __restrict__ bias, uint2* __restrict__ outH, int n)
{
  __shared__ float s_ex[4][64];
  __shared__ int   s_col[4][64];
  int w = threadIdx.x >> 6, lane = threadIdx.x & 63;
  int node = blockIdx.x * 4 + w;
  if (node >= n) return;
  int beg = off[node], end = off[node + 1];
  float adv = ad_[node];
  int sub = lane >> 4, c = lane & 15;

  float exs = expf(lrelu(as_[node] + adv));          // self-loop, sub 0 only
  uint2 hv0 = H2[(size_t)node * 16 + c];
  float2 s01 = __half22float2(*(__half2*)&hv0.x);
  float2 s23 = __half22float2(*(__half2*)&hv0.y);
  float e0 = (sub == 0) ? exs : 0.f;
  float denom = e0;
  float a0 = e0 * s01.x, a1 = e0 * s01.y, a2 = e0 * s23.x, a3 = e0 * s23.y;

  for (int cb = beg; cb < end; cb += 64){
    int cnt = end - cb; if (cnt > 64) cnt = 64;
    float ex = 0.f; int s = 0;
    if (lane < cnt){ s = col[cb + lane]; ex = expf(lrelu(as_[s] + adv)); }
    s_ex[w][lane] = ex; s_col[w][lane] = s;          // wave-local, lockstep
    #pragma unroll 2
    for (int j = 0; j < cnt; j += 4){
      int jj = j + sub;
      float e = 0.f; int sj = 0;
      if (jj < cnt){ e = s_ex[w][jj]; sj = s_col[w][jj]; }
      uint2 hv = H2[(size_t)sj * 16 + c];
      float2 f01 = __half22float2(*(__half2*)&hv.x);
      float2 f23 = __half22float2(*(__half2*)&hv.y);
      denom += e;
      a0 = fmaf(e, f01.x, a0); a1 = fmaf(e, f01.y, a1);
      a2 = fmaf(e, f23.x, a2); a3 = fmaf(e, f23.y, a3);
    }
  }
  denom += __shfl_xor(denom, 16, 64); denom += __shfl_xor(denom, 32, 64);
  a0 += __shfl_xor(a0, 16, 64); a0 += __shfl_xor(a0, 32, 64);
  a1 += __shfl_xor(a1, 16, 64); a1 += __shfl_xor(a1, 32, 64);
  a2 += __shfl_xor(a2, 16, 64); a2 += __shfl_xor(a2, 32, 64);
  a3 += __shfl_xor(a3, 16, 64); a3 += __shfl_xor(a3, 32, 64);
  if (sub == 0){
    float inv = 1.f / denom;
    float4 b4 = *(const float4*)&bias[4 * c];
    float v0 = elu_f(fmaf(a0, inv, b4.x));
    float v1 = elu_f(fmaf(a1, inv, b4.y));
    float v2 = elu_f(fmaf(a2, inv, b4.z));
    float v3 = elu_f(fmaf(a3, inv, b4.w));
    __half2 o01 = __floats2half2_rn(v0, v1);
    __half2 o23 = __floats2half2_rn(v2, v3);
    uint2 ov; ov.x = *(unsigned*)&o01; ov.y = *(unsigned*)&o23;
    outH[(size_t)node * 16 + c] = ov;
  }
}

__global__ __launch_bounds__(256) void k_agg2(
    const int* __restrict__ off, const int* __restrict__ col,
    const uint2* __restrict__ H2, const float* __restrict__ as_, const float* __restrict__ ad_,
    const float* __restrict__ bias, const float* __restrict__ Wout, const float* __restrict__ bout,
    float* __restrict__ out, int n)
{
  __shared__ float s_ex[4][64];
  __shared__ int   s_col[4][64];
  int w = threadIdx.x >> 6, lane = threadIdx.x & 63;
  int node = blockIdx.x * 4 + w;
  if (node >= n) return;
  int beg = off[node], end = off[node + 1];
  float adv = ad_[node];
  int sub = lane >> 4, c = lane & 15;

  float exs = expf(lrelu(as_[node] + adv));
  uint2 hv0 = H2[(size_t)node * 16 + c];
  float2 s01 = __half22float2(*(__half2*)&hv0.x);
  float2 s23 = __half22float2(*(__half2*)&hv0.y);
  float e0 = (sub == 0) ? exs : 0.f;
  float denom = e0;
  float a0 = e0 * s01.x, a1 = e0 * s01.y, a2 = e0 * s23.x, a3 = e0 * s23.y;

  for (int cb = beg; cb < end; cb += 64){
    int cnt = end - cb; if (cnt > 64) cnt = 64;
    float ex = 0.f; int s = 0;
    if (lane < cnt){ s = col[cb + lane]; ex = expf(lrelu(as_[s] + adv)); }
    s_ex[w][lane] = ex; s_col[w][lane] = s;
    #pragma unroll 2
    for (int j = 0; j < cnt; j += 4){
      int jj = j + sub;
      float e = 0.f; int sj = 0;
      if (jj < cnt){ e = s_ex[w][jj]; sj = s_col[w][jj]; }
      uint2 hv = H2[(size_t)sj * 16 + c];
      float2 f01 = __half22float2(*(__half2*)&hv.x);
      float2 f23 = __half22float2(*(__half2*)&hv.y);
      denom += e;
      a0 = fmaf(e, f01.x, a0); a1 = fmaf(e, f01.y, a1);
      a2 = fmaf(e, f23.x, a2); a3 = fmaf(e, f23.y, a3);
    }
  }
  denom += __shfl_xor(denom, 16, 64); denom += __shfl_xor(denom, 32, 64);
  a0 += __shfl_xor(a0, 16, 64); a0 += __shfl_xor(a0, 32, 64);
  a1 += __shfl_xor(a1, 16, 64); a1 += __shfl_xor(a1, 32, 64);
  a2 += __shfl_xor(a2, 16, 64); a2 += __shfl_xor(a2, 32, 64);
  a3 += __shfl_xor(a3, 16, 64); a3 += __shfl_xor(a3, 32, 64);
  float inv = 1.f / denom;
  float4 b4 = *(const float4*)&bias[4 * c];
  float4 w4 = *(const float4*)&Wout[4 * c];
  float p = elu_f(fmaf(a0, inv, b4.x)) * w4.x
          + elu_f(fmaf(a1, inv, b4.y)) * w4.y
          + elu_f(fmaf(a2, inv, b4.z)) * w4.z
          + elu_f(fmaf(a3, inv, b4.w)) * w4.w;
  p += __shfl_xor(p, 1, 64); p += __shfl_xor(p, 2, 64);
  p += __shfl_xor(p, 4, 64); p += __shfl_xor(p, 8, 64);
  if (lane == 0) out[node] = p + bout[0];
}

// ---------------- launch ----------------
extern "C" void kernel_launch(void* const* d_in, const int* in_sizes, int n_in,
                              void* d_out, int out_size, void* d_ws, size_t ws_size,
                              hipStream_t stream)
{
  const float* x    = (const float*)d_in[0];
  const int*   ei   = (const int*)d_in[1];   // int32 [2, E] flat
  const float* W1   = (const float*)d_in[2];
  const float* as1w = (const float*)d_in[3];
  const float* ad1w = (const float*)d_in[4];
  const float* b1   = (const float*)d_in[5];
  const float* W2   = (const float*)d_in[6];
  const float* as2w = (const float*)d_in[7];
  const float* ad2w = (const float*)d_in[8];
  const float* b2   = (const float*)d_in[9];
  const float* Wout = (const float*)d_in[10];
  const float* bout = (const float*)d_in[11];
  float* out = (float*)d_out;

  const int N = in_sizes[0] / 128;
  const int E = in_sizes[1] / 2;
  const int* srcA = ei;
  const int* dstA = ei + E;
  const int B = (N + BKT_NODES - 1) >> BKT_SHIFT;   // 98 (<= BKT_CAP); src < 2^17 required

  char* p = (char*)d_ws;
  auto alloc = [&](size_t bytes){ char* r = p; p += (bytes + 255) & ~255ull; return r; };
  int*   bktTot   = (int*)alloc(BKT_CAP * 4);
  int*   bktStart = (int*)alloc((BKT_CAP + 1) * 4);
  int*   bktCur   = (int*)alloc(BKT_CAP * 4);
  int*   offs     = (int*)alloc((size_t)(N + 1) * 4);
  int*   col      = (int*)alloc((size_t)E * 4);
  float* vas1 = (float*)alloc((size_t)N * 4);
  float* vad1 = (float*)alloc((size_t)N * 4);
  float* vas2 = (float*)alloc((size_t)N * 4);
  float* vad2 = (float*)alloc((size_t)N * 4);
  uint2* h1   = (uint2*)alloc((size_t)N * 64 * 2);   // fp16 [N,64]
  uint2* h1e  = (uint2*)alloc((size_t)N * 64 * 2);   // fp16 [N,64]
  unsigned* pairs = (unsigned*)h1;  // pairs (E*4B=6.4MB) dead before k_gemm writes h1 (12.8MB)
  uint2* h2   = h1;                 // h1 dead after k_agg1

  hipMemsetAsync(bktTot, 0, BKT_CAP * 4, stream);

  int nchunk = (E + P1_CHUNK - 1) / P1_CHUNK;
  k_bh   <<<nchunk, 256, 0, stream>>>(dstA, E, B, bktTot);
  k_bscan<<<1, BKT_CAP, 0, stream>>>(bktTot, B, E, N, bktStart, bktCur, offs);
  k_p1   <<<nchunk, 256, 0, stream>>>(srcA, dstA, E, B, bktCur, pairs);
  k_p2   <<<B, 1024, 0, stream>>>(pairs, bktStart, N, offs, col);

  k_gemm<128,false><<<(N + 63) / 64, 256, 0, stream>>>(x, W1, as1w, ad1w, h1, vas1, vad1, N);
  k_agg1           <<<(N + 3) / 4, 256, 0, stream>>>(offs, col, h1, vas1, vad1, b1, h1e, N);
  k_gemm<64,true>  <<<(N + 63) / 64, 256, 0, stream>>>(h1e, W2, as2w, ad2w, h2, vas2, vad2, N);
  k_agg2           <<<(N + 3) / 4, 256, 0, stream>>>(offs, col, h2, vas2, vad2, b2, Wout, bout, out, N);
}

// Round 5
// 314.341 us; speedup vs baseline: 1.5706x; 1.0313x over previous
//
#include <hip/hip_runtime.h>
#include <hip/hip_fp16.h>
#include <math.h>

#define NEG_SLOPE 0.2f
#define BKT_SHIFT 10
#define BKT_NODES (1 << BKT_SHIFT)
#define BKT_CAP 128
#define P1_CHUNK 8192

__device__ __forceinline__ float lrelu(float x){ return fmaxf(x, NEG_SLOPE * x); }
__device__ __forceinline__ float elu_fast(float x){
  float t = __expf(fminf(x, 0.f)) - 1.f;
  return x > 0.f ? x : t;
}

// ---------------- bucketed CSR build ----------------
// bucket b = dst >> BKT_SHIFT. pairs packed: (dst&1023)<<17 | src  (src < 2^17)

__global__ __launch_bounds__(256) void k_bh(const int* __restrict__ dst, int E, int B,
                                            int* __restrict__ bktTot){
  __shared__ int h[BKT_CAP];
  int tid = threadIdx.x;
  if (tid < BKT_CAP) h[tid] = 0;
  __syncthreads();
  int beg = blockIdx.x * P1_CHUNK;
  int end = min(beg + P1_CHUNK, E);
  for (int i = beg + tid; i < end; i += 256)
    atomicAdd(&h[dst[i] >> BKT_SHIFT], 1);
  __syncthreads();
  if (tid < B && h[tid]) atomicAdd(&bktTot[tid], h[tid]);
}

__global__ void k_bscan(const int* __restrict__ bktTot, int B, int E, int N,
                        int* __restrict__ bktStart, int* __restrict__ bktCur,
                        int* __restrict__ offs){
  __shared__ int tmp[BKT_CAP];
  int t = threadIdx.x;
  int v = (t < B) ? bktTot[t] : 0;
  tmp[t] = v; __syncthreads();
  for (int o = 1; o < BKT_CAP; o <<= 1){
    int x = (t >= o) ? tmp[t - o] : 0;
    __syncthreads();
    tmp[t] += x;
    __syncthreads();
  }
  if (t < B){ int st = tmp[t] - v; bktStart[t] = st; bktCur[t] = st; }
  if (t == 0){ bktStart[B] = E; offs[N] = E; }
}

__global__ __launch_bounds__(256) void k_p1(const int* __restrict__ src, const int* __restrict__ dst,
                                            int E, int B, int* __restrict__ bktCur,
                                            unsigned* __restrict__ pairs){
  __shared__ int h[BKT_CAP], base[BKT_CAP], cur[BKT_CAP];
  int tid = threadIdx.x;
  if (tid < BKT_CAP){ h[tid] = 0; cur[tid] = 0; }
  __syncthreads();
  int beg = blockIdx.x * P1_CHUNK;
  int end = min(beg + P1_CHUNK, E);
  for (int i = beg + tid; i < end; i += 256)
    atomicAdd(&h[dst[i] >> BKT_SHIFT], 1);
  __syncthreads();
  if (tid < B && h[tid]) base[tid] = atomicAdd(&bktCur[tid], h[tid]);
  __syncthreads();
  for (int i = beg + tid; i < end; i += 256){
    int d = dst[i], s = src[i];
    int b = d >> BKT_SHIFT;
    int p = base[b] + atomicAdd(&cur[b], 1);
    pairs[p] = ((unsigned)(d & (BKT_NODES - 1)) << 17) | (unsigned)s;
  }
}

// one block per bucket: LDS node-hist -> in-block scan -> offs + col
__global__ __launch_bounds__(1024) void k_p2(const unsigned* __restrict__ pairs,
                                             const int* __restrict__ bktStart,
                                             int N, int* __restrict__ offs, int* __restrict__ col){
  __shared__ int sc[BKT_NODES], cu[BKT_NODES];
  int b = blockIdx.x, tid = threadIdx.x;
  int nbase = b << BKT_SHIFT;
  int bs = bktStart[b], be = bktStart[b + 1];
  sc[tid] = 0;
  __syncthreads();
  for (int i = bs + tid; i < be; i += 1024)
    atomicAdd(&sc[pairs[i] >> 17], 1);
  __syncthreads();
  int v = sc[tid];
  for (int o = 1; o < 1024; o <<= 1){
    int x = (tid >= o) ? sc[tid - o] : 0;
    __syncthreads();
    sc[tid] += x;
    __syncthreads();
  }
  int ex = sc[tid] - v;
  cu[tid] = bs + ex;
  if (nbase + tid < N) offs[nbase + tid] = bs + ex;
  __syncthreads();
  for (int i = bs + tid; i < be; i += 1024){
    unsigned pr = pairs[i];
    int p = atomicAdd(&cu[pr >> 17], 1);
    col[p] = (int)(pr & 0x1FFFFu);
  }
}

// ---------------- node GEMM: H(fp16) = X @ W  (+ fp32 attention logits) ----------------
template<int K, bool HIN>
__global__ __launch_bounds__(256) void k_gemm(
    const void* __restrict__ Xv, const float* __restrict__ W,
    const float* __restrict__ a_src, const float* __restrict__ a_dst,
    uint2* __restrict__ H2, float* __restrict__ as_, float* __restrict__ ad_, int n)
{
  __shared__ float sW[K * 64];
  __shared__ float sX[32 * 68];
  const int tid = threadIdx.x;
  for (int i = tid; i < K * 16; i += 256)
    ((float4*)sW)[i] = ((const float4*)W)[i];

  const int cg = tid & 15;
  const int nr = tid >> 4;
  const int nodeBase = blockIdx.x * 64;
  float acc[4][4] = {};

  for (int kc = 0; kc < K; kc += 32){
    __syncthreads();
    for (int e = tid; e < 64 * 32; e += 256){
      int nn = e >> 5, kk = e & 31;
      int gn = nodeBase + nn; if (gn >= n) gn = n - 1;
      float xv;
      if (HIN) xv = __half2float(((const __half*)Xv)[(size_t)gn * K + kc + kk]);
      else     xv = ((const float*)Xv)[(size_t)gn * K + kc + kk];
      sX[kk * 68 + nn] = xv;
    }
    __syncthreads();
    #pragma unroll
    for (int kk = 0; kk < 32; ++kk){
      float4 xv = *(const float4*)&sX[kk * 68 + nr * 4];
      float4 wv = *(const float4*)&sW[(kc + kk) * 64 + cg * 4];
      float xs[4] = {xv.x, xv.y, xv.z, xv.w};
      float ws[4] = {wv.x, wv.y, wv.z, wv.w};
      #pragma unroll
      for (int a = 0; a < 4; ++a)
        #pragma unroll
        for (int b = 0; b < 4; ++b)
          acc[a][b] = fmaf(xs[a], ws[b], acc[a][b]);
    }
  }

  float a_s[4], a_d[4];
  #pragma unroll
  for (int c = 0; c < 4; ++c){ a_s[c] = a_src[cg * 4 + c]; a_d[c] = a_dst[cg * 4 + c]; }
  #pragma unroll
  for (int i2 = 0; i2 < 4; ++i2){
    int gn = nodeBase + nr * 4 + i2;
    float sl = acc[i2][0]*a_s[0] + acc[i2][1]*a_s[1] + acc[i2][2]*a_s[2] + acc[i2][3]*a_s[3];
    float dl = acc[i2][0]*a_d[0] + acc[i2][1]*a_d[1] + acc[i2][2]*a_d[2] + acc[i2][3]*a_d[3];
    #pragma unroll
    for (int o = 1; o < 16; o <<= 1){ sl += __shfl_xor(sl, o, 64); dl += __shfl_xor(dl, o, 64); }
    if (gn < n){
      __half2 h01 = __floats2half2_rn(acc[i2][0], acc[i2][1]);
      __half2 h23 = __floats2half2_rn(acc[i2][2], acc[i2][3]);
      uint2 ov; ov.x = *(unsigned*)&h01; ov.y = *(unsigned*)&h23;
      H2[(size_t)gn * 16 + cg] = ov;
      if (cg == 0){ as_[gn] = sl; ad_[gn] = dl; }
    }
  }
}

// ---------------- attention aggregation: 8 edges/wave-iter, uint4 fp16 gathers ----------------
// lane = (sub=lane>>3 -> edge j+sub, c8=lane&7 -> channels 8*c8 .. 8*c8+7)
__global__ __launch_bounds__(256) void k_agg1(
    const int* __restrict__ off, const int* __restrict__ col,
    const uint4* __restrict__ H4, const float* __restrict__ as_, const float* __restrict__ ad_,
    const float* __restrict__ bias, uint4* __restrict__ outH, int n)
{
  __shared__ uint2 s_ec[4][64];          // (col, ex bits)
  int w = threadIdx.x >> 6, lane = threadIdx.x & 63;
  int node = blockIdx.x * 4 + w;
  if (node >= n) return;
  int beg = off[node], end = off[node + 1];
  float adv = ad_[node];
  int sub = lane >> 3, c8 = lane & 7;
  const uint4* Hc = H4 + c8;

  // self-loop (sub 0 only)
  float exs = __expf(lrelu(as_[node] + adv));
  float e0 = (sub == 0) ? exs : 0.f;
  float denom = e0;
  float a[8];
  {
    uint4 hs = Hc[(size_t)node * 8];
    const __half2* hp = (const __half2*)&hs;
    #pragma unroll
    for (int i = 0; i < 4; ++i){
      a[2*i]   = e0 * __half2float(hp[i].x);
      a[2*i+1] = e0 * __half2float(hp[i].y);
    }
  }

  for (int cb = beg; cb < end; cb += 64){
    int cnt = end - cb; if (cnt > 64) cnt = 64;
    float ex = 0.f; int s = 0;
    if (lane < cnt){ s = col[cb + lane]; ex = __expf(lrelu(as_[s] + adv)); }
    s_ec[w][lane] = make_uint2((unsigned)s, __float_as_uint(ex));   // wave-local, lockstep
    #pragma unroll 2
    for (int j = 0; j < cnt; j += 8){
      uint2 ec = s_ec[w][j + sub];       // j+sub <= 63 always; padding slots hold ex=0
      float e = __uint_as_float(ec.y);
      uint4 hv = Hc[(size_t)ec.x * 8];
      const __half2* hp = (const __half2*)&hv;
      denom += e;
      #pragma unroll
      for (int i = 0; i < 4; ++i){
        a[2*i]   = fmaf(e, __half2float(hp[i].x), a[2*i]);
        a[2*i+1] = fmaf(e, __half2float(hp[i].y), a[2*i+1]);
      }
    }
  }
  #pragma unroll
  for (int o = 8; o < 64; o <<= 1){
    denom += __shfl_xor(denom, o, 64);
    #pragma unroll
    for (int i = 0; i < 8; ++i) a[i] += __shfl_xor(a[i], o, 64);
  }
  if (sub == 0){
    float inv = 1.f / denom;
    float4 b0 = *(const float4*)&bias[8 * c8];
    float4 b1 = *(const float4*)&bias[8 * c8 + 4];
    float bb[8] = {b0.x, b0.y, b0.z, b0.w, b1.x, b1.y, b1.z, b1.w};
    unsigned oh[4];
    #pragma unroll
    for (int i = 0; i < 4; ++i){
      float v0 = elu_fast(fmaf(a[2*i],   inv, bb[2*i]));
      float v1 = elu_fast(fmaf(a[2*i+1], inv, bb[2*i+1]));
      __half2 h = __floats2half2_rn(v0, v1);
      oh[i] = *(unsigned*)&h;
    }
    uint4 ov; ov.x = oh[0]; ov.y = oh[1]; ov.z = oh[2]; ov.w = oh[3];
    outH[(size_t)node * 8 + c8] = ov;
  }
}

__global__ __launch_bounds__(256) void k_agg2(
    const int* __restrict__ off, const int* __restrict__ col,
    const uint4* __restrict__ H4, const float* __restrict__ as_, const float* __restrict__ ad_,
    const float* __restrict__ bias, const float* __restrict__ Wout, const float* __restrict__ bout,
    float* __restrict__ out, int n)
{
  __shared__ uint2 s_ec[4][64];
  int w = threadIdx.x >> 6, lane = threadIdx.x & 63;
  int node = blockIdx.x * 4 + w;
  if (node >= n) return;
  int beg = off[node], end = off[node + 1];
  float adv = ad_[node];
  int sub = lane >> 3, c8 = lane & 7;
  const uint4* Hc = H4 + c8;

  float exs = __expf(lrelu(as_[node] + adv));
  float e0 = (sub == 0) ? exs : 0.f;
  float denom = e0;
  float a[8];
  {
    uint4 hs = Hc[(size_t)node * 8];
    const __half2* hp = (const __half2*)&hs;
    #pragma unroll
    for (int i = 0; i < 4; ++i){
      a[2*i]   = e0 * __half2float(hp[i].x);
      a[2*i+1] = e0 * __half2float(hp[i].y);
    }
  }

  for (int cb = beg; cb < end; cb += 64){
    int cnt = end - cb; if (cnt > 64) cnt = 64;
    float ex = 0.f; int s = 0;
    if (lane < cnt){ s = col[cb + lane]; ex = __expf(lrelu(as_[s] + adv)); }
    s_ec[w][lane] = make_uint2((unsigned)s, __float_as_uint(ex));
    #pragma unroll 2
    for (int j = 0; j < cnt; j += 8){
      uint2 ec = s_ec[w][j + sub];
      float e = __uint_as_float(ec.y);
      uint4 hv = Hc[(size_t)ec.x * 8];
      const __half2* hp = (const __half2*)&hv;
      denom += e;
      #pragma unroll
      for (int i = 0; i < 4; ++i){
        a[2*i]   = fmaf(e, __half2float(hp[i].x), a[2*i]);
        a[2*i+1] = fmaf(e, __half2float(hp[i].y), a[2*i+1]);
      }
    }
  }
  #pragma unroll
  for (int o = 8; o < 64; o <<= 1){
    denom += __shfl_xor(denom, o, 64);
    #pragma unroll
    for (int i = 0; i < 8; ++i) a[i] += __shfl_xor(a[i], o, 64);
  }
  float inv = 1.f / denom;
  float4 b0 = *(const float4*)&bias[8 * c8];
  float4 b1 = *(const float4*)&bias[8 * c8 + 4];
  float4 w0 = *(const float4*)&Wout[8 * c8];
  float4 w1 = *(const float4*)&Wout[8 * c8 + 4];
  float bb[8] = {b0.x, b0.y, b0.z, b0.w, b1.x, b1.y, b1.z, b1.w};
  float ww[8] = {w0.x, w0.y, w0.z, w0.w, w1.x, w1.y, w1.z, w1.w};
  float p = 0.f;
  #pragma unroll
  for (int i = 0; i < 8; ++i)
    p += elu_fast(fmaf(a[i], inv, bb[i])) * ww[i];
  p = (sub == 0) ? p : 0.f;
  p += __shfl_xor(p, 1, 64); p += __shfl_xor(p, 2, 64); p += __shfl_xor(p, 4, 64);
  if (lane == 0) out[node] = p + bout[0];
}

// ---------------- launch ----------------
extern "C" void kernel_launch(void* const* d_in, const int* in_sizes, int n_in,
                              void* d_out, int out_size, void* d_ws, size_t ws_size,
                              hipStream_t stream)
{
  const float* x    = (const float*)d_in[0];
  const int*   ei   = (const int*)d_in[1];   // int32 [2, E] flat
  const float* W1   = (const float*)d_in[2];
  const float* as1w = (const float*)d_in[3];
  const float* ad1w = (const float*)d_in[4];
  const float* b1   = (const float*)d_in[5];
  const float* W2   = (const float*)d_in[6];
  const float* as2w = (const float*)d_in[7];
  const float* ad2w = (const float*)d_in[8];
  const float* b2   = (const float*)d_in[9];
  const float* Wout = (const float*)d_in[10];
  const float* bout = (const float*)d_in[11];
  float* out = (float*)d_out;

  const int N = in_sizes[0] / 128;
  const int E = in_sizes[1] / 2;
  const int* srcA = ei;
  const int* dstA = ei + E;
  const int B = (N + BKT_NODES - 1) >> BKT_SHIFT;   // 98 (<= BKT_CAP); src < 2^17 required

  char* p = (char*)d_ws;
  auto alloc = [&](size_t bytes){ char* r = p; p += (bytes + 255) & ~255ull; return r; };
  int*   bktTot   = (int*)alloc(BKT_CAP * 4);
  int*   bktStart = (int*)alloc((BKT_CAP + 1) * 4);
  int*   bktCur   = (int*)alloc(BKT_CAP * 4);
  int*   offs     = (int*)alloc((size_t)(N + 1) * 4);
  int*   col      = (int*)alloc((size_t)E * 4);
  float* vas1 = (float*)alloc((size_t)N * 4);
  float* vad1 = (float*)alloc((size_t)N * 4);
  float* vas2 = (float*)alloc((size_t)N * 4);
  float* vad2 = (float*)alloc((size_t)N * 4);
  uint2* h1   = (uint2*)alloc((size_t)N * 64 * 2);   // fp16 [N,64]
  uint2* h1e  = (uint2*)alloc((size_t)N * 64 * 2);   // fp16 [N,64]
  unsigned* pairs = (unsigned*)h1;  // pairs (E*4B=6.4MB) dead before k_gemm writes h1 (12.8MB)
  uint2* h2   = h1;                 // h1 dead after k_agg1

  hipMemsetAsync(bktTot, 0, BKT_CAP * 4, stream);

  int nchunk = (E + P1_CHUNK - 1) / P1_CHUNK;
  k_bh   <<<nchunk, 256, 0, stream>>>(dstA, E, B, bktTot);
  k_bscan<<<1, BKT_CAP, 0, stream>>>(bktTot, B, E, N, bktStart, bktCur, offs);
  k_p1   <<<nchunk, 256, 0, stream>>>(srcA, dstA, E, B, bktCur, pairs);
  k_p2   <<<B, 1024, 0, stream>>>(pairs, bktStart, N, offs, col);

  k_gemm<128,false><<<(N + 63) / 64, 256, 0, stream>>>(x, W1, as1w, ad1w, h1, vas1, vad1, N);
  k_agg1           <<<(N + 3) / 4, 256, 0, stream>>>(offs, col, (const uint4*)h1, vas1, vad1, b1, (uint4*)h1e, N);
  k_gemm<64,true>  <<<(N + 63) / 64, 256, 0, stream>>>(h1e, W2, as2w, ad2w, h2, vas2, vad2, N);
  k_agg2           <<<(N + 3) / 4, 256, 0, stream>>>(offs, col, (const uint4*)h2, vas2, vad2, b2, Wout, bout, out, N);
}

// Round 6
// 283.592 us; speedup vs baseline: 1.7409x; 1.1084x over previous
//
#include <hip/hip_runtime.h>
#include <hip/hip_fp16.h>
#include <math.h>

#define NEG_SLOPE 0.2f
#define BKT_SHIFT 10
#define BKT_NODES (1 << BKT_SHIFT)
#define BKT_CAP 128
#define P1_CHUNK 8192

typedef _Float16 f16x8 __attribute__((ext_vector_type(8)));
typedef float    f32x4 __attribute__((ext_vector_type(4)));
union FU  { uint4 u; f16x8 f; };
union H2U { __half2 h; unsigned u; };

__device__ __forceinline__ float lrelu(float x){ return fmaxf(x, NEG_SLOPE * x); }
__device__ __forceinline__ float elu_fast(float x){
  float t = __expf(fminf(x, 0.f)) - 1.f;
  return x > 0.f ? x : t;
}

// ---------------- bucketed CSR build ----------------
__global__ __launch_bounds__(256) void k_bh(const int* __restrict__ dst, int E, int B,
                                            int* __restrict__ bktTot){
  __shared__ int h[BKT_CAP];
  int tid = threadIdx.x;
  if (tid < BKT_CAP) h[tid] = 0;
  __syncthreads();
  int beg = blockIdx.x * P1_CHUNK;
  int end = min(beg + P1_CHUNK, E);
  for (int i = beg + tid; i < end; i += 256)
    atomicAdd(&h[dst[i] >> BKT_SHIFT], 1);
  __syncthreads();
  if (tid < B && h[tid]) atomicAdd(&bktTot[tid], h[tid]);
}

__global__ void k_bscan(const int* __restrict__ bktTot, int B, int E, int N,
                        int* __restrict__ bktStart, int* __restrict__ bktCur,
                        int* __restrict__ offs){
  __shared__ int tmp[BKT_CAP];
  int t = threadIdx.x;
  int v = (t < B) ? bktTot[t] : 0;
  tmp[t] = v; __syncthreads();
  for (int o = 1; o < BKT_CAP; o <<= 1){
    int x = (t >= o) ? tmp[t - o] : 0;
    __syncthreads();
    tmp[t] += x;
    __syncthreads();
  }
  if (t < B){ int st = tmp[t] - v; bktStart[t] = st; bktCur[t] = st; }
  if (t == 0){ bktStart[B] = E; offs[N] = E; }
}

__global__ __launch_bounds__(256) void k_p1(const int* __restrict__ src, const int* __restrict__ dst,
                                            int E, int B, int* __restrict__ bktCur,
                                            unsigned* __restrict__ pairs){
  __shared__ int h[BKT_CAP], base[BKT_CAP], cur[BKT_CAP];
  int tid = threadIdx.x;
  if (tid < BKT_CAP){ h[tid] = 0; cur[tid] = 0; }
  __syncthreads();
  int beg = blockIdx.x * P1_CHUNK;
  int end = min(beg + P1_CHUNK, E);
  for (int i = beg + tid; i < end; i += 256)
    atomicAdd(&h[dst[i] >> BKT_SHIFT], 1);
  __syncthreads();
  if (tid < B && h[tid]) base[tid] = atomicAdd(&bktCur[tid], h[tid]);
  __syncthreads();
  for (int i = beg + tid; i < end; i += 256){
    int d = dst[i], s = src[i];
    int b = d >> BKT_SHIFT;
    int p = base[b] + atomicAdd(&cur[b], 1);
    pairs[p] = ((unsigned)(d & (BKT_NODES - 1)) << 17) | (unsigned)s;
  }
}

__global__ __launch_bounds__(1024) void k_p2(const unsigned* __restrict__ pairs,
                                             const int* __restrict__ bktStart,
                                             int N, int* __restrict__ offs, int* __restrict__ col){
  __shared__ int sc[BKT_NODES], cu[BKT_NODES];
  int b = blockIdx.x, tid = threadIdx.x;
  int nbase = b << BKT_SHIFT;
  int bs = bktStart[b], be = bktStart[b + 1];
  sc[tid] = 0;
  __syncthreads();
  for (int i = bs + tid; i < be; i += 1024)
    atomicAdd(&sc[pairs[i] >> 17], 1);
  __syncthreads();
  int v = sc[tid];
  for (int o = 1; o < 1024; o <<= 1){
    int x = (tid >= o) ? sc[tid - o] : 0;
    __syncthreads();
    sc[tid] += x;
    __syncthreads();
  }
  int ex = sc[tid] - v;
  cu[tid] = bs + ex;
  if (nbase + tid < N) offs[nbase + tid] = bs + ex;
  __syncthreads();
  for (int i = bs + tid; i < be; i += 1024){
    unsigned pr = pairs[i];
    int p = atomicAdd(&cu[pr >> 17], 1);
    col[p] = (int)(pr & 0x1FFFFu);
  }
}

// ---------------- W fragment prepack (A-operand layout, H^T orientation) ----------------
// Afrag[t][s][lane] holds W[k = s*32 + quad*8 + j][t*16 + m], m=lane&15, quad=lane>>4, j=0..7
__global__ __launch_bounds__(1024) void k_packW(const float* __restrict__ W1,
                                                const float* __restrict__ W2,
                                                uint4* __restrict__ W1f, uint4* __restrict__ W2f){
  int tid = threadIdx.x;
  {
    int lane = tid & 63, fs = tid >> 6;       // fs = t*4 + s  (t,s in 0..3)
    int t = fs >> 2, s = fs & 3;
    int m = lane & 15, quad = lane >> 4;
    f16x8 v;
    #pragma unroll
    for (int j = 0; j < 8; ++j)
      v[j] = (_Float16)W1[(s * 32 + quad * 8 + j) * 64 + t * 16 + m];
    FU fu; fu.f = v;
    W1f[fs * 64 + lane] = fu.u;
  }
  if (tid < 512){
    int lane = tid & 63, fs = tid >> 6;       // fs = t*2 + s  (t in 0..3, s in 0..1)
    int t = fs >> 1, s = fs & 1;
    int m = lane & 15, quad = lane >> 4;
    f16x8 v;
    #pragma unroll
    for (int j = 0; j < 8; ++j)
      v[j] = (_Float16)W2[(s * 32 + quad * 8 + j) * 64 + t * 16 + m];
    FU fu; fu.f = v;
    W2f[fs * 64 + lane] = fu.u;
  }
}

// ---------------- MFMA GEMM 1: H(fp16)[n,64] = X(fp32)[n,128] @ W1, + logits ----------------
// wave: 16 rows x 64 cols. D tile t: lane holds H[row=rowb+(lane&15)][t*16+quad*4+reg]
__global__ __launch_bounds__(256) void k_mgemm1(
    const float* __restrict__ X, const uint4* __restrict__ Wf,
    const float* __restrict__ a_src, const float* __restrict__ a_dst,
    uint2* __restrict__ H, float* __restrict__ as_, float* __restrict__ ad_, int n)
{
  int lane = threadIdx.x & 63, wv = threadIdx.x >> 6;
  int quad = lane >> 4, nn = lane & 15;
  int rowb = blockIdx.x * 64 + wv * 16;
  int row = rowb + nn;
  bool ok = row < n;
  int rowc = ok ? row : n - 1;

  f16x8 af[4][4];
  #pragma unroll
  for (int t = 0; t < 4; ++t)
    #pragma unroll
    for (int s = 0; s < 4; ++s){
      FU fu; fu.u = Wf[(t * 4 + s) * 64 + lane];
      af[t][s] = fu.f;
    }

  const float4* Xr = (const float4*)(X + (size_t)rowc * 128);
  float4 xb[4][2];
  #pragma unroll
  for (int s = 0; s < 4; ++s){
    xb[s][0] = Xr[s * 8 + quad * 2];
    xb[s][1] = Xr[s * 8 + quad * 2 + 1];
  }

  f32x4 acc[4] = {};
  #pragma unroll
  for (int s = 0; s < 4; ++s){
    f16x8 bf;
    bf[0] = (_Float16)xb[s][0].x; bf[1] = (_Float16)xb[s][0].y;
    bf[2] = (_Float16)xb[s][0].z; bf[3] = (_Float16)xb[s][0].w;
    bf[4] = (_Float16)xb[s][1].x; bf[5] = (_Float16)xb[s][1].y;
    bf[6] = (_Float16)xb[s][1].z; bf[7] = (_Float16)xb[s][1].w;
    #pragma unroll
    for (int t = 0; t < 4; ++t)
      acc[t] = __builtin_amdgcn_mfma_f32_16x16x32_f16(af[t][s], bf, acc[t], 0, 0, 0);
  }

  if (ok){
    #pragma unroll
    for (int t = 0; t < 4; ++t){
      H2U p0, p1;
      p0.h = __floats2half2_rn(acc[t][0], acc[t][1]);
      p1.h = __floats2half2_rn(acc[t][2], acc[t][3]);
      H[(size_t)row * 16 + t * 4 + quad] = make_uint2(p0.u, p1.u);
    }
  }
  float sl = 0.f, dl = 0.f;
  #pragma unroll
  for (int t = 0; t < 4; ++t){
    float4 a4 = ((const float4*)a_src)[t * 4 + quad];
    float4 d4 = ((const float4*)a_dst)[t * 4 + quad];
    sl += acc[t][0] * a4.x + acc[t][1] * a4.y + acc[t][2] * a4.z + acc[t][3] * a4.w;
    dl += acc[t][0] * d4.x + acc[t][1] * d4.y + acc[t][2] * d4.z + acc[t][3] * d4.w;
  }
  sl += __shfl_xor(sl, 16, 64); sl += __shfl_xor(sl, 32, 64);
  dl += __shfl_xor(dl, 16, 64); dl += __shfl_xor(dl, 32, 64);
  if (lane < 16 && ok){ as_[row] = sl; ad_[row] = dl; }
}

// ---------------- MFMA GEMM 2: h2(fp16) = h1e(fp16)[n,64] @ W2, + logits ----------------
__global__ __launch_bounds__(256) void k_mgemm2(
    const uint4* __restrict__ Xh, const uint4* __restrict__ Wf,
    const float* __restrict__ a_src, const float* __restrict__ a_dst,
    uint2* __restrict__ H, float* __restrict__ as_, float* __restrict__ ad_, int n)
{
  int lane = threadIdx.x & 63, wv = threadIdx.x >> 6;
  int quad = lane >> 4, nn = lane & 15;
  int rowb = blockIdx.x * 64 + wv * 16;
  int row = rowb + nn;
  bool ok = row < n;
  int rowc = ok ? row : n - 1;

  f16x8 af[4][2];
  #pragma unroll
  for (int t = 0; t < 4; ++t)
    #pragma unroll
    for (int s = 0; s < 2; ++s){
      FU fu; fu.u = Wf[(t * 2 + s) * 64 + lane];
      af[t][s] = fu.f;
    }

  f16x8 bf[2];
  #pragma unroll
  for (int s = 0; s < 2; ++s){
    FU fu; fu.u = Xh[(size_t)rowc * 8 + s * 4 + quad];
    bf[s] = fu.f;
  }

  f32x4 acc[4] = {};
  #pragma unroll
  for (int s = 0; s < 2; ++s)
    #pragma unroll
    for (int t = 0; t < 4; ++t)
      acc[t] = __builtin_amdgcn_mfma_f32_16x16x32_f16(af[t][s], bf[s], acc[t], 0, 0, 0);

  if (ok){
    #pragma unroll
    for (int t = 0; t < 4; ++t){
      H2U p0, p1;
      p0.h = __floats2half2_rn(acc[t][0], acc[t][1]);
      p1.h = __floats2half2_rn(acc[t][2], acc[t][3]);
      H[(size_t)row * 16 + t * 4 + quad] = make_uint2(p0.u, p1.u);
    }
  }
  float sl = 0.f, dl = 0.f;
  #pragma unroll
  for (int t = 0; t < 4; ++t){
    float4 a4 = ((const float4*)a_src)[t * 4 + quad];
    float4 d4 = ((const float4*)a_dst)[t * 4 + quad];
    sl += acc[t][0] * a4.x + acc[t][1] * a4.y + acc[t][2] * a4.z + acc[t][3] * a4.w;
    dl += acc[t][0] * d4.x + acc[t][1] * d4.y + acc[t][2] * d4.z + acc[t][3] * d4.w;
  }
  sl += __shfl_xor(sl, 16, 64); sl += __shfl_xor(sl, 32, 64);
  dl += __shfl_xor(dl, 16, 64); dl += __shfl_xor(dl, 32, 64);
  if (lane < 16 && ok){ as_[row] = sl; ad_[row] = dl; }
}

// ---------------- attention aggregation: 8 edges/wave-iter, uint4 fp16 gathers ----------------
__global__ __launch_bounds__(256) void k_agg1(
    const int* __restrict__ off, const int* __restrict__ col,
    const uint4* __restrict__ H4, const float* __restrict__ as_, const float* __restrict__ ad_,
    const float* __restrict__ bias, uint4* __restrict__ outH, int n)
{
  __shared__ uint2 s_ec[4][64];
  int w = threadIdx.x >> 6, lane = threadIdx.x & 63;
  int node = blockIdx.x * 4 + w;
  if (node >= n) return;
  int beg = off[node], end = off[node + 1];
  float adv = ad_[node];
  int sub = lane >> 3, c8 = lane & 7;
  const uint4* Hc = H4 + c8;

  float exs = __expf(lrelu(as_[node] + adv));
  float e0 = (sub == 0) ? exs : 0.f;
  float denom = e0;
  float a[8];
  {
    uint4 hs = Hc[(size_t)node * 8];
    const __half2* hp = (const __half2*)&hs;
    #pragma unroll
    for (int i = 0; i < 4; ++i){
      a[2*i]   = e0 * __half2float(hp[i].x);
      a[2*i+1] = e0 * __half2float(hp[i].y);
    }
  }

  for (int cb = beg; cb < end; cb += 64){
    int cnt = end - cb; if (cnt > 64) cnt = 64;
    float ex = 0.f; int s = 0;
    if (lane < cnt){ s = col[cb + lane]; ex = __expf(lrelu(as_[s] + adv)); }
    s_ec[w][lane] = make_uint2((unsigned)s, __float_as_uint(ex));
    #pragma unroll 2
    for (int j = 0; j < cnt; j += 8){
      uint2 ec = s_ec[w][j + sub];
      float e = __uint_as_float(ec.y);
      uint4 hv = Hc[(size_t)ec.x * 8];
      const __half2* hp = (const __half2*)&hv;
      denom += e;
      #pragma unroll
      for (int i = 0; i < 4; ++i){
        a[2*i]   = fmaf(e, __half2float(hp[i].x), a[2*i]);
        a[2*i+1] = fmaf(e, __half2float(hp[i].y), a[2*i+1]);
      }
    }
  }
  #pragma unroll
  for (int o = 8; o < 64; o <<= 1){
    denom += __shfl_xor(denom, o, 64);
    #pragma unroll
    for (int i = 0; i < 8; ++i) a[i] += __shfl_xor(a[i], o, 64);
  }
  if (sub == 0){
    float inv = 1.f / denom;
    float4 b0 = *(const float4*)&bias[8 * c8];
    float4 b1 = *(const float4*)&bias[8 * c8 + 4];
    float bb[8] = {b0.x, b0.y, b0.z, b0.w, b1.x, b1.y, b1.z, b1.w};
    unsigned oh[4];
    #pragma unroll
    for (int i = 0; i < 4; ++i){
      float v0 = elu_fast(fmaf(a[2*i],   inv, bb[2*i]));
      float v1 = elu_fast(fmaf(a[2*i+1], inv, bb[2*i+1]));
      __half2 h = __floats2half2_rn(v0, v1);
      oh[i] = *(unsigned*)&h;
    }
    uint4 ov; ov.x = oh[0]; ov.y = oh[1]; ov.z = oh[2]; ov.w = oh[3];
    outH[(size_t)node * 8 + c8] = ov;
  }
}

__global__ __launch_bounds__(256) void k_agg2(
    const int* __restrict__ off, const int* __restrict__ col,
    const uint4* __restrict__ H4, const float* __restrict__ as_, const float* __restrict__ ad_,
    const float* __restrict__ bias, const float* __restrict__ Wout, const float* __restrict__ bout,
    float* __restrict__ out, int n)
{
  __shared__ uint2 s_ec[4][64];
  int w = threadIdx.x >> 6, lane = threadIdx.x & 63;
  int node = blockIdx.x * 4 + w;
  if (node >= n) return;
  int beg = off[node], end = off[node + 1];
  float adv = ad_[node];
  int sub = lane >> 3, c8 = lane & 7;
  const uint4* Hc = H4 + c8;

  float exs = __expf(lrelu(as_[node] + adv));
  float e0 = (sub == 0) ? exs : 0.f;
  float denom = e0;
  float a[8];
  {
    uint4 hs = Hc[(size_t)node * 8];
    const __half2* hp = (const __half2*)&hs;
    #pragma unroll
    for (int i = 0; i < 4; ++i){
      a[2*i]   = e0 * __half2float(hp[i].x);
      a[2*i+1] = e0 * __half2float(hp[i].y);
    }
  }

  for (int cb = beg; cb < end; cb += 64){
    int cnt = end - cb; if (cnt > 64) cnt = 64;
    float ex = 0.f; int s = 0;
    if (lane < cnt){ s = col[cb + lane]; ex = __expf(lrelu(as_[s] + adv)); }
    s_ec[w][lane] = make_uint2((unsigned)s, __float_as_uint(ex));
    #pragma unroll 2
    for (int j = 0; j < cnt; j += 8){
      uint2 ec = s_ec[w][j + sub];
      float e = __uint_as_float(ec.y);
      uint4 hv = Hc[(size_t)ec.x * 8];
      const __half2* hp = (const __half2*)&hv;
      denom += e;
      #pragma unroll
      for (int i = 0; i < 4; ++i){
        a[2*i]   = fmaf(e, __half2float(hp[i].x), a[2*i]);
        a[2*i+1] = fmaf(e, __half2float(hp[i].y), a[2*i+1]);
      }
    }
  }
  #pragma unroll
  for (int o = 8; o < 64; o <<= 1){
    denom += __shfl_xor(denom, o, 64);
    #pragma unroll
    for (int i = 0; i < 8; ++i) a[i] += __shfl_xor(a[i], o, 64);
  }
  float inv = 1.f / denom;
  float4 b0 = *(const float4*)&bias[8 * c8];
  float4 b1 = *(const float4*)&bias[8 * c8 + 4];
  float4 w0 = *(const float4*)&Wout[8 * c8];
  float4 w1 = *(const float4*)&Wout[8 * c8 + 4];
  float bb[8] = {b0.x, b0.y, b0.z, b0.w, b1.x, b1.y, b1.z, b1.w};
  float ww[8] = {w0.x, w0.y, w0.z, w0.w, w1.x, w1.y, w1.z, w1.w};
  float p = 0.f;
  #pragma unroll
  for (int i = 0; i < 8; ++i)
    p += elu_fast(fmaf(a[i], inv, bb[i])) * ww[i];
  p = (sub == 0) ? p : 0.f;
  p += __shfl_xor(p, 1, 64); p += __shfl_xor(p, 2, 64); p += __shfl_xor(p, 4, 64);
  if (lane == 0) out[node] = p + bout[0];
}

// ---------------- launch ----------------
extern "C" void kernel_launch(void* const* d_in, const int* in_sizes, int n_in,
                              void* d_out, int out_size, void* d_ws, size_t ws_size,
                              hipStream_t stream)
{
  const float* x    = (const float*)d_in[0];
  const int*   ei   = (const int*)d_in[1];   // int32 [2, E] flat
  const float* W1   = (const float*)d_in[2];
  const float* as1w = (const float*)d_in[3];
  const float* ad1w = (const float*)d_in[4];
  const float* b1   = (const float*)d_in[5];
  const float* W2   = (const float*)d_in[6];
  const float* as2w = (const float*)d_in[7];
  const float* ad2w = (const float*)d_in[8];
  const float* b2   = (const float*)d_in[9];
  const float* Wout = (const float*)d_in[10];
  const float* bout = (const float*)d_in[11];
  float* out = (float*)d_out;

  const int N = in_sizes[0] / 128;
  const int E = in_sizes[1] / 2;
  const int* srcA = ei;
  const int* dstA = ei + E;
  const int B = (N + BKT_NODES - 1) >> BKT_SHIFT;   // 98 (<= BKT_CAP); src < 2^17 required

  char* p = (char*)d_ws;
  auto alloc = [&](size_t bytes){ char* r = p; p += (bytes + 255) & ~255ull; return r; };
  int*   bktTot   = (int*)alloc(BKT_CAP * 4);
  int*   bktStart = (int*)alloc((BKT_CAP + 1) * 4);
  int*   bktCur   = (int*)alloc(BKT_CAP * 4);
  int*   offs     = (int*)alloc((size_t)(N + 1) * 4);
  int*   col      = (int*)alloc((size_t)E * 4);
  float* vas1 = (float*)alloc((size_t)N * 4);
  float* vad1 = (float*)alloc((size_t)N * 4);
  float* vas2 = (float*)alloc((size_t)N * 4);
  float* vad2 = (float*)alloc((size_t)N * 4);
  uint4* w1f  = (uint4*)alloc(16 * 64 * 16);         // 16 frags x 64 lanes x 16B
  uint4* w2f  = (uint4*)alloc(8 * 64 * 16);
  uint2* h1   = (uint2*)alloc((size_t)N * 64 * 2);   // fp16 [N,64]
  uint2* h1e  = (uint2*)alloc((size_t)N * 64 * 2);   // fp16 [N,64]
  unsigned* pairs = (unsigned*)h1;  // pairs (E*4B=6.4MB) dead before k_mgemm1 writes h1 (12.8MB)
  uint2* h2   = h1;                 // h1 dead after k_agg1

  hipMemsetAsync(bktTot, 0, BKT_CAP * 4, stream);

  int nchunk = (E + P1_CHUNK - 1) / P1_CHUNK;
  k_packW<<<1, 1024, 0, stream>>>(W1, W2, w1f, w2f);
  k_bh   <<<nchunk, 256, 0, stream>>>(dstA, E, B, bktTot);
  k_bscan<<<1, BKT_CAP, 0, stream>>>(bktTot, B, E, N, bktStart, bktCur, offs);
  k_p1   <<<nchunk, 256, 0, stream>>>(srcA, dstA, E, B, bktCur, pairs);
  k_p2   <<<B, 1024, 0, stream>>>(pairs, bktStart, N, offs, col);

  int gblocks = (N + 63) / 64;
  k_mgemm1<<<gblocks, 256, 0, stream>>>(x, w1f, as1w, ad1w, h1, vas1, vad1, N);
  k_agg1  <<<(N + 3) / 4, 256, 0, stream>>>(offs, col, (const uint4*)h1, vas1, vad1, b1, (uint4*)h1e, N);
  k_mgemm2<<<gblocks, 256, 0, stream>>>((const uint4*)h1e, w2f, as2w, ad2w, h2, vas2, vad2, N);
  k_agg2  <<<(N + 3) / 4, 256, 0, stream>>>(offs, col, (const uint4*)h2, vas2, vad2, b2, Wout, bout, out, N);
}

// Round 7
// 275.726 us; speedup vs baseline: 1.7906x; 1.0285x over previous
//
#include <hip/hip_runtime.h>
#include <hip/hip_fp16.h>
#include <math.h>

#define NEG_SLOPE 0.2f
#define BKT_SHIFT 8
#define BKT_NODES (1 << BKT_SHIFT)       // 256 nodes per bucket
#define BKT_CAP 512                      // >= B = ceil(N/256) = 391
#define P1_CHUNK 4096

typedef _Float16 f16x8 __attribute__((ext_vector_type(8)));
typedef float    f32x4 __attribute__((ext_vector_type(4)));
union FU  { uint4 u; f16x8 f; };
union H2U { __half2 h; unsigned u; };

__device__ __forceinline__ float lrelu(float x){ return fmaxf(x, NEG_SLOPE * x); }
__device__ __forceinline__ float elu_fast(float x){
  float t = __expf(fminf(x, 0.f)) - 1.f;
  return x > 0.f ? x : t;
}

// ---------------- bucketed CSR build ----------------
// bucket b = dst >> 8. pairs packed: (dst&255)<<17 | src  (src < 2^17)

__global__ __launch_bounds__(256) void k_bh(const int* __restrict__ dst, int E, int B,
                                            int* __restrict__ bktTot){
  __shared__ int h[BKT_CAP];
  int tid = threadIdx.x;
  for (int i = tid; i < BKT_CAP; i += 256) h[i] = 0;
  __syncthreads();
  int beg = blockIdx.x * P1_CHUNK;
  int end = min(beg + P1_CHUNK, E);
  int m4 = (end - beg) >> 2;
  const int4* d4 = (const int4*)(dst + beg);
  for (int i = tid; i < m4; i += 256){
    int4 d = d4[i];
    atomicAdd(&h[d.x >> BKT_SHIFT], 1); atomicAdd(&h[d.y >> BKT_SHIFT], 1);
    atomicAdd(&h[d.z >> BKT_SHIFT], 1); atomicAdd(&h[d.w >> BKT_SHIFT], 1);
  }
  for (int i = beg + (m4 << 2) + tid; i < end; i += 256)
    atomicAdd(&h[dst[i] >> BKT_SHIFT], 1);
  __syncthreads();
  for (int i = tid; i < B; i += 256)
    if (h[i]) atomicAdd(&bktTot[i], h[i]);
}

__global__ __launch_bounds__(512) void k_bscan(const int* __restrict__ bktTot, int B, int E, int N,
                        int* __restrict__ bktStart, int* __restrict__ bktCur,
                        int* __restrict__ offs){
  __shared__ int tmp[BKT_CAP];
  int t = threadIdx.x;
  int v = (t < B) ? bktTot[t] : 0;
  tmp[t] = v; __syncthreads();
  for (int o = 1; o < BKT_CAP; o <<= 1){
    int x = (t >= o) ? tmp[t - o] : 0;
    __syncthreads();
    tmp[t] += x;
    __syncthreads();
  }
  if (t < B){ int st = tmp[t] - v; bktStart[t] = st; bktCur[t] = st; }
  if (t == 0){ bktStart[B] = E; offs[N] = E; }
}

__global__ __launch_bounds__(256) void k_p1(const int* __restrict__ src, const int* __restrict__ dst,
                                            int E, int B, int* __restrict__ bktCur,
                                            unsigned* __restrict__ pairs){
  __shared__ int h[BKT_CAP], base[BKT_CAP], cur[BKT_CAP];
  int tid = threadIdx.x;
  for (int i = tid; i < BKT_CAP; i += 256){ h[i] = 0; cur[i] = 0; }
  __syncthreads();
  int beg = blockIdx.x * P1_CHUNK;
  int end = min(beg + P1_CHUNK, E);
  int m4 = (end - beg) >> 2;
  const int4* d4 = (const int4*)(dst + beg);
  const int4* s4 = (const int4*)(src + beg);
  for (int i = tid; i < m4; i += 256){
    int4 d = d4[i];
    atomicAdd(&h[d.x >> BKT_SHIFT], 1); atomicAdd(&h[d.y >> BKT_SHIFT], 1);
    atomicAdd(&h[d.z >> BKT_SHIFT], 1); atomicAdd(&h[d.w >> BKT_SHIFT], 1);
  }
  for (int i = beg + (m4 << 2) + tid; i < end; i += 256)
    atomicAdd(&h[dst[i] >> BKT_SHIFT], 1);
  __syncthreads();
  for (int i = tid; i < B; i += 256)
    if (h[i]) base[i] = atomicAdd(&bktCur[i], h[i]);
  __syncthreads();
  for (int i = tid; i < m4; i += 256){
    int4 d = d4[i]; int4 s = s4[i];
    int b0 = d.x >> BKT_SHIFT, b1 = d.y >> BKT_SHIFT, b2 = d.z >> BKT_SHIFT, b3 = d.w >> BKT_SHIFT;
    int p0 = base[b0] + atomicAdd(&cur[b0], 1);
    pairs[p0] = ((unsigned)(d.x & (BKT_NODES-1)) << 17) | (unsigned)s.x;
    int p1 = base[b1] + atomicAdd(&cur[b1], 1);
    pairs[p1] = ((unsigned)(d.y & (BKT_NODES-1)) << 17) | (unsigned)s.y;
    int p2 = base[b2] + atomicAdd(&cur[b2], 1);
    pairs[p2] = ((unsigned)(d.z & (BKT_NODES-1)) << 17) | (unsigned)s.z;
    int p3 = base[b3] + atomicAdd(&cur[b3], 1);
    pairs[p3] = ((unsigned)(d.w & (BKT_NODES-1)) << 17) | (unsigned)s.w;
  }
  for (int i = beg + (m4 << 2) + tid; i < end; i += 256){
    int d = dst[i], s = src[i];
    int b = d >> BKT_SHIFT;
    int p = base[b] + atomicAdd(&cur[b], 1);
    pairs[p] = ((unsigned)(d & (BKT_NODES-1)) << 17) | (unsigned)s;
  }
}

// one block (256 thr) per bucket of 256 nodes
__global__ __launch_bounds__(256) void k_p2(const unsigned* __restrict__ pairs,
                                            const int* __restrict__ bktStart,
                                            int N, int* __restrict__ offs, int* __restrict__ col){
  __shared__ int sc[BKT_NODES], cu[BKT_NODES];
  int b = blockIdx.x, tid = threadIdx.x;
  int nbase = b << BKT_SHIFT;
  int bs = bktStart[b], be = bktStart[b + 1];
  sc[tid] = 0;
  __syncthreads();
  for (int i = bs + tid; i < be; i += 256)
    atomicAdd(&sc[pairs[i] >> 17], 1);
  __syncthreads();
  int v = sc[tid];
  for (int o = 1; o < 256; o <<= 1){
    int x = (tid >= o) ? sc[tid - o] : 0;
    __syncthreads();
    sc[tid] += x;
    __syncthreads();
  }
  int ex = sc[tid] - v;
  cu[tid] = bs + ex;
  if (nbase + tid < N) offs[nbase + tid] = bs + ex;
  __syncthreads();
  for (int i = bs + tid; i < be; i += 256){
    unsigned pr = pairs[i];
    int p = atomicAdd(&cu[pr >> 17], 1);
    col[p] = (int)(pr & 0x1FFFFu);
  }
}

// ---------------- W fragment prepack (A-operand layout, H^T orientation) ----------------
__global__ __launch_bounds__(1024) void k_packW(const float* __restrict__ W1,
                                                const float* __restrict__ W2,
                                                uint4* __restrict__ W1f, uint4* __restrict__ W2f){
  int tid = threadIdx.x;
  {
    int lane = tid & 63, fs = tid >> 6;       // fs = t*4 + s
    int t = fs >> 2, s = fs & 3;
    int m = lane & 15, quad = lane >> 4;
    f16x8 v;
    #pragma unroll
    for (int j = 0; j < 8; ++j)
      v[j] = (_Float16)W1[(s * 32 + quad * 8 + j) * 64 + t * 16 + m];
    FU fu; fu.f = v;
    W1f[fs * 64 + lane] = fu.u;
  }
  if (tid < 512){
    int lane = tid & 63, fs = tid >> 6;       // fs = t*2 + s
    int t = fs >> 1, s = fs & 1;
    int m = lane & 15, quad = lane >> 4;
    f16x8 v;
    #pragma unroll
    for (int j = 0; j < 8; ++j)
      v[j] = (_Float16)W2[(s * 32 + quad * 8 + j) * 64 + t * 16 + m];
    FU fu; fu.f = v;
    W2f[fs * 64 + lane] = fu.u;
  }
}

// ---------------- MFMA GEMM 1: H(fp16)[n,64] = X(fp32)[n,128] @ W1, + logits ----------------
__global__ __launch_bounds__(256) void k_mgemm1(
    const float* __restrict__ X, const uint4* __restrict__ Wf,
    const float* __restrict__ a_src, const float* __restrict__ a_dst,
    uint2* __restrict__ H, float* __restrict__ as_, float* __restrict__ ad_, int n)
{
  int lane = threadIdx.x & 63, wv = threadIdx.x >> 6;
  int quad = lane >> 4, nn = lane & 15;
  int rowb = blockIdx.x * 64 + wv * 16;
  int row = rowb + nn;
  bool ok = row < n;
  int rowc = ok ? row : n - 1;

  f16x8 af[4][4];
  #pragma unroll
  for (int t = 0; t < 4; ++t)
    #pragma unroll
    for (int s = 0; s < 4; ++s){
      FU fu; fu.u = Wf[(t * 4 + s) * 64 + lane];
      af[t][s] = fu.f;
    }

  const float4* Xr = (const float4*)(X + (size_t)rowc * 128);
  float4 xb[4][2];
  #pragma unroll
  for (int s = 0; s < 4; ++s){
    xb[s][0] = Xr[s * 8 + quad * 2];
    xb[s][1] = Xr[s * 8 + quad * 2 + 1];
  }

  f32x4 acc[4] = {};
  #pragma unroll
  for (int s = 0; s < 4; ++s){
    f16x8 bf;
    bf[0] = (_Float16)xb[s][0].x; bf[1] = (_Float16)xb[s][0].y;
    bf[2] = (_Float16)xb[s][0].z; bf[3] = (_Float16)xb[s][0].w;
    bf[4] = (_Float16)xb[s][1].x; bf[5] = (_Float16)xb[s][1].y;
    bf[6] = (_Float16)xb[s][1].z; bf[7] = (_Float16)xb[s][1].w;
    #pragma unroll
    for (int t = 0; t < 4; ++t)
      acc[t] = __builtin_amdgcn_mfma_f32_16x16x32_f16(af[t][s], bf, acc[t], 0, 0, 0);
  }

  if (ok){
    #pragma unroll
    for (int t = 0; t < 4; ++t){
      H2U p0, p1;
      p0.h = __floats2half2_rn(acc[t][0], acc[t][1]);
      p1.h = __floats2half2_rn(acc[t][2], acc[t][3]);
      H[(size_t)row * 16 + t * 4 + quad] = make_uint2(p0.u, p1.u);
    }
  }
  float sl = 0.f, dl = 0.f;
  #pragma unroll
  for (int t = 0; t < 4; ++t){
    float4 a4 = ((const float4*)a_src)[t * 4 + quad];
    float4 d4 = ((const float4*)a_dst)[t * 4 + quad];
    sl += acc[t][0] * a4.x + acc[t][1] * a4.y + acc[t][2] * a4.z + acc[t][3] * a4.w;
    dl += acc[t][0] * d4.x + acc[t][1] * d4.y + acc[t][2] * d4.z + acc[t][3] * d4.w;
  }
  sl += __shfl_xor(sl, 16, 64); sl += __shfl_xor(sl, 32, 64);
  dl += __shfl_xor(dl, 16, 64); dl += __shfl_xor(dl, 32, 64);
  if (lane < 16 && ok){ as_[row] = sl; ad_[row] = dl; }
}

// ---------------- MFMA GEMM 2: h2(fp16) = h1e(fp16)[n,64] @ W2, + logits ----------------
__global__ __launch_bounds__(256) void k_mgemm2(
    const uint4* __restrict__ Xh, const uint4* __restrict__ Wf,
    const float* __restrict__ a_src, const float* __restrict__ a_dst,
    uint2* __restrict__ H, float* __restrict__ as_, float* __restrict__ ad_, int n)
{
  int lane = threadIdx.x & 63, wv = threadIdx.x >> 6;
  int quad = lane >> 4, nn = lane & 15;
  int rowb = blockIdx.x * 64 + wv * 16;
  int row = rowb + nn;
  bool ok = row < n;
  int rowc = ok ? row : n - 1;

  f16x8 af[4][2];
  #pragma unroll
  for (int t = 0; t < 4; ++t)
    #pragma unroll
    for (int s = 0; s < 2; ++s){
      FU fu; fu.u = Wf[(t * 2 + s) * 64 + lane];
      af[t][s] = fu.f;
    }

  f16x8 bf[2];
  #pragma unroll
  for (int s = 0; s < 2; ++s){
    FU fu; fu.u = Xh[(size_t)rowc * 8 + s * 4 + quad];
    bf[s] = fu.f;
  }

  f32x4 acc[4] = {};
  #pragma unroll
  for (int s = 0; s < 2; ++s)
    #pragma unroll
    for (int t = 0; t < 4; ++t)
      acc[t] = __builtin_amdgcn_mfma_f32_16x16x32_f16(af[t][s], bf[s], acc[t], 0, 0, 0);

  if (ok){
    #pragma unroll
    for (int t = 0; t < 4; ++t){
      H2U p0, p1;
      p0.h = __floats2half2_rn(acc[t][0], acc[t][1]);
      p1.h = __floats2half2_rn(acc[t][2], acc[t][3]);
      H[(size_t)row * 16 + t * 4 + quad] = make_uint2(p0.u, p1.u);
    }
  }
  float sl = 0.f, dl = 0.f;
  #pragma unroll
  for (int t = 0; t < 4; ++t){
    float4 a4 = ((const float4*)a_src)[t * 4 + quad];
    float4 d4 = ((const float4*)a_dst)[t * 4 + quad];
    sl += acc[t][0] * a4.x + acc[t][1] * a4.y + acc[t][2] * a4.z + acc[t][3] * a4.w;
    dl += acc[t][0] * d4.x + acc[t][1] * d4.y + acc[t][2] * d4.z + acc[t][3] * d4.w;
  }
  sl += __shfl_xor(sl, 16, 64); sl += __shfl_xor(sl, 32, 64);
  dl += __shfl_xor(dl, 16, 64); dl += __shfl_xor(dl, 32, 64);
  if (lane < 16 && ok){ as_[row] = sl; ad_[row] = dl; }
}

// ---------------- attention aggregation: 32 edges/iter, 4 gathers in flight ----------------
// lane = (sub=lane>>3 -> edge slot, c8=lane&7 -> 8 channels). LDS slots zero-padded to 64.
#define AGG_BODY \
  float exs = __expf(lrelu(as_[node] + adv));                                   \
  float e0s = (sub == 0) ? exs : 0.f;                                           \
  float denom = e0s;                                                            \
  float a[8];                                                                   \
  {                                                                             \
    uint4 hs = Hc[(size_t)node * 8];                                            \
    const __half2* hp = (const __half2*)&hs;                                    \
    _Pragma("unroll")                                                           \
    for (int i = 0; i < 4; ++i){                                                \
      a[2*i]   = e0s * __half2float(hp[i].x);                                   \
      a[2*i+1] = e0s * __half2float(hp[i].y);                                   \
    }                                                                           \
  }                                                                             \
  for (int cb = beg; cb < end; cb += 64){                                       \
    int cnt = end - cb; if (cnt > 64) cnt = 64;                                 \
    float ex = 0.f; int s = 0;                                                  \
    if (lane < cnt){ s = col[cb + lane]; ex = __expf(lrelu(as_[s] + adv)); }    \
    s_ec[w][lane] = make_uint2((unsigned)s, __float_as_uint(ex));               \
    for (int j = 0; j < cnt; j += 32){                                          \
      uint2 ec0 = s_ec[w][j + sub];                                             \
      uint2 ec1 = s_ec[w][j + 8 + sub];                                         \
      uint2 ec2 = s_ec[w][j + 16 + sub];                                        \
      uint2 ec3 = s_ec[w][j + 24 + sub];                                        \
      uint4 hv0 = Hc[(size_t)ec0.x * 8];                                        \
      uint4 hv1 = Hc[(size_t)ec1.x * 8];                                        \
      uint4 hv2 = Hc[(size_t)ec2.x * 8];                                        \
      uint4 hv3 = Hc[(size_t)ec3.x * 8];                                        \
      float e0 = __uint_as_float(ec0.y), e1 = __uint_as_float(ec1.y);           \
      float e2 = __uint_as_float(ec2.y), e3 = __uint_as_float(ec3.y);           \
      denom += (e0 + e1) + (e2 + e3);                                           \
      const __half2* p0 = (const __half2*)&hv0;                                 \
      const __half2* p1 = (const __half2*)&hv1;                                 \
      const __half2* p2 = (const __half2*)&hv2;                                 \
      const __half2* p3 = (const __half2*)&hv3;                                 \
      _Pragma("unroll")                                                         \
      for (int i = 0; i < 4; ++i){                                              \
        a[2*i]   = fmaf(e0, __half2float(p0[i].x), a[2*i]);                     \
        a[2*i+1] = fmaf(e0, __half2float(p0[i].y), a[2*i+1]);                   \
        a[2*i]   = fmaf(e1, __half2float(p1[i].x), a[2*i]);                     \
        a[2*i+1] = fmaf(e1, __half2float(p1[i].y), a[2*i+1]);                   \
        a[2*i]   = fmaf(e2, __half2float(p2[i].x), a[2*i]);                     \
        a[2*i+1] = fmaf(e2, __half2float(p2[i].y), a[2*i+1]);                   \
        a[2*i]   = fmaf(e3, __half2float(p3[i].x), a[2*i]);                     \
        a[2*i+1] = fmaf(e3, __half2float(p3[i].y), a[2*i+1]);                   \
      }                                                                         \
    }                                                                           \
  }                                                                             \
  _Pragma("unroll")                                                             \
  for (int o = 8; o < 64; o <<= 1){                                             \
    denom += __shfl_xor(denom, o, 64);                                          \
    _Pragma("unroll")                                                           \
    for (int i = 0; i < 8; ++i) a[i] += __shfl_xor(a[i], o, 64);                \
  }

__global__ __launch_bounds__(256) void k_agg1(
    const int* __restrict__ off, const int* __restrict__ col,
    const uint4* __restrict__ H4, const float* __restrict__ as_, const float* __restrict__ ad_,
    const float* __restrict__ bias, uint4* __restrict__ outH, int n)
{
  __shared__ uint2 s_ec[4][64];
  int w = threadIdx.x >> 6, lane = threadIdx.x & 63;
  int node = blockIdx.x * 4 + w;
  if (node >= n) return;
  int beg = off[node], end = off[node + 1];
  float adv = ad_[node];
  int sub = lane >> 3, c8 = lane & 7;
  const uint4* Hc = H4 + c8;
  AGG_BODY
  if (sub == 0){
    float inv = 1.f / denom;
    float4 b0 = *(const float4*)&bias[8 * c8];
    float4 b1 = *(const float4*)&bias[8 * c8 + 4];
    float bb[8] = {b0.x, b0.y, b0.z, b0.w, b1.x, b1.y, b1.z, b1.w};
    unsigned oh[4];
    #pragma unroll
    for (int i = 0; i < 4; ++i){
      float v0 = elu_fast(fmaf(a[2*i],   inv, bb[2*i]));
      float v1 = elu_fast(fmaf(a[2*i+1], inv, bb[2*i+1]));
      __half2 h = __floats2half2_rn(v0, v1);
      oh[i] = *(unsigned*)&h;
    }
    uint4 ov; ov.x = oh[0]; ov.y = oh[1]; ov.z = oh[2]; ov.w = oh[3];
    outH[(size_t)node * 8 + c8] = ov;
  }
}

__global__ __launch_bounds__(256) void k_agg2(
    const int* __restrict__ off, const int* __restrict__ col,
    const uint4* __restrict__ H4, const float* __restrict__ as_, const float* __restrict__ ad_,
    const float* __restrict__ bias, const float* __restrict__ Wout, const float* __restrict__ bout,
    float* __restrict__ out, int n)
{
  __shared__ uint2 s_ec[4][64];
  int w = threadIdx.x >> 6, lane = threadIdx.x & 63;
  int node = blockIdx.x * 4 + w;
  if (node >= n) return;
  int beg = off[node], end = off[node + 1];
  float adv = ad_[node];
  int sub = lane >> 3, c8 = lane & 7;
  const uint4* Hc = H4 + c8;
  AGG_BODY
  float inv = 1.f / denom;
  float4 b0 = *(const float4*)&bias[8 * c8];
  float4 b1 = *(const float4*)&bias[8 * c8 + 4];
  float4 w0 = *(const float4*)&Wout[8 * c8];
  float4 w1 = *(const float4*)&Wout[8 * c8 + 4];
  float bb[8] = {b0.x, b0.y, b0.z, b0.w, b1.x, b1.y, b1.z, b1.w};
  float ww[8] = {w0.x, w0.y, w0.z, w0.w, w1.x, w1.y, w1.z, w1.w};
  float p = 0.f;
  #pragma unroll
  for (int i = 0; i < 8; ++i)
    p += elu_fast(fmaf(a[i], inv, bb[i])) * ww[i];
  p = (sub == 0) ? p : 0.f;
  p += __shfl_xor(p, 1, 64); p += __shfl_xor(p, 2, 64); p += __shfl_xor(p, 4, 64);
  if (lane == 0) out[node] = p + bout[0];
}

// ---------------- launch ----------------
extern "C" void kernel_launch(void* const* d_in, const int* in_sizes, int n_in,
                              void* d_out, int out_size, void* d_ws, size_t ws_size,
                              hipStream_t stream)
{
  const float* x    = (const float*)d_in[0];
  const int*   ei   = (const int*)d_in[1];   // int32 [2, E] flat
  const float* W1   = (const float*)d_in[2];
  const float* as1w = (const float*)d_in[3];
  const float* ad1w = (const float*)d_in[4];
  const float* b1   = (const float*)d_in[5];
  const float* W2   = (const float*)d_in[6];
  const float* as2w = (const float*)d_in[7];
  const float* ad2w = (const float*)d_in[8];
  const float* b2   = (const float*)d_in[9];
  const float* Wout = (const float*)d_in[10];
  const float* bout = (const float*)d_in[11];
  float* out = (float*)d_out;

  const int N = in_sizes[0] / 128;
  const int E = in_sizes[1] / 2;
  const int* srcA = ei;
  const int* dstA = ei + E;
  const int B = (N + BKT_NODES - 1) >> BKT_SHIFT;   // 391 (<= BKT_CAP); src < 2^17 required

  char* p = (char*)d_ws;
  auto alloc = [&](size_t bytes){ char* r = p; p += (bytes + 255) & ~255ull; return r; };
  int*   bktTot   = (int*)alloc(BKT_CAP * 4);
  int*   bktStart = (int*)alloc((BKT_CAP + 1) * 4);
  int*   bktCur   = (int*)alloc(BKT_CAP * 4);
  int*   offs     = (int*)alloc((size_t)(N + 1) * 4);
  int*   col      = (int*)alloc((size_t)E * 4);
  float* vas1 = (float*)alloc((size_t)N * 4);
  float* vad1 = (float*)alloc((size_t)N * 4);
  float* vas2 = (float*)alloc((size_t)N * 4);
  float* vad2 = (float*)alloc((size_t)N * 4);
  uint4* w1f  = (uint4*)alloc(16 * 64 * 16);
  uint4* w2f  = (uint4*)alloc(8 * 64 * 16);
  uint2* h1   = (uint2*)alloc((size_t)N * 64 * 2);   // fp16 [N,64]
  uint2* h1e  = (uint2*)alloc((size_t)N * 64 * 2);   // fp16 [N,64]
  unsigned* pairs = (unsigned*)h1;  // pairs (E*4B) dead before k_mgemm1 writes h1
  uint2* h2   = h1;                 // h1 dead after k_agg1

  hipMemsetAsync(bktTot, 0, BKT_CAP * 4, stream);

  int nchunk = (E + P1_CHUNK - 1) / P1_CHUNK;
  k_packW<<<1, 1024, 0, stream>>>(W1, W2, w1f, w2f);
  k_bh   <<<nchunk, 256, 0, stream>>>(dstA, E, B, bktTot);
  k_bscan<<<1, BKT_CAP, 0, stream>>>(bktTot, B, E, N, bktStart, bktCur, offs);
  k_p1   <<<nchunk, 256, 0, stream>>>(srcA, dstA, E, B, bktCur, pairs);
  k_p2   <<<B, 256, 0, stream>>>(pairs, bktStart, N, offs, col);

  int gblocks = (N + 63) / 64;
  k_mgemm1<<<gblocks, 256, 0, stream>>>(x, w1f, as1w, ad1w, h1, vas1, vad1, N);
  k_agg1  <<<(N + 3) / 4, 256, 0, stream>>>(offs, col, (const uint4*)h1, vas1, vad1, b1, (uint4*)h1e, N);
  k_mgemm2<<<gblocks, 256, 0, stream>>>((const uint4*)h1e, w2f, as2w, ad2w, h2, vas2, vad2, N);
  k_agg2  <<<(N + 3) / 4, 256, 0, stream>>>(offs, col, (const uint4*)h2, vas2, vad2, b2, Wout, bout, out, N);
}